// Round 5
// baseline (20492.589 us; speedup 1.0000x reference)
//
#include <hip/hip_runtime.h>
#include <math.h>

#define B_     128
#define L_     100
#define HID_   256
#define IND_   160
#define NCLASS 19
#define CAPD   16
#define NI     1600      // L_ * NUM_CAPS
#define OD     304       // NCLASS * CAPD
#define ENTITY 68

// scan weight partition (of 128 k-pair slices): register / LDS / streamed
#define NREG   64
#define NLDS   20
#define PSTRM  (NREG + NLDS)     // 84
#define NSTRM  (128 - PSTRM)     // 44

typedef _Float16 half2_t __attribute__((ext_vector_type(2)));

__device__ inline half2_t as_h2(unsigned u) {
    union { unsigned u; half2_t h; } x; x.u = u; return x.h;
}
__device__ inline unsigned pack2(float a, float b) {
    union { unsigned u; half2_t h; } x;
    x.h = (half2_t){ (_Float16)a, (_Float16)b };   // RTN converts
    return x.u;
}
__device__ inline float fdot2_(unsigned w, unsigned h, float acc) {
#if __has_builtin(__builtin_amdgcn_fdot2)
    return __builtin_amdgcn_fdot2(as_h2(w), as_h2(h), acc, false);
#else
    half2_t wh = as_h2(w), hh = as_h2(h);
    acc = fmaf((float)wh.x, (float)hh.x, acc);
    return fmaf((float)wh.y, (float)hh.y, acc);
#endif
}

// ---------------------------------------------------------------------------
// Phase 0: embedding gather -> emb [b*L_+t][160]
// ---------------------------------------------------------------------------
__global__ void emb_gather(const int* __restrict__ word, const int* __restrict__ tag,
                           const int* __restrict__ pos1, const int* __restrict__ pos2,
                           const float* __restrict__ we, const float* __restrict__ te,
                           const float* __restrict__ p1e, const float* __restrict__ p2e,
                           float* __restrict__ emb)
{
    int idx = blockIdx.x * 256 + threadIdx.x;          // exactly B_*L_*IND_ threads
    int bt = idx / IND_;
    int k  = idx - bt * IND_;
    float v;
    if (k < 100)      v = we[word[bt] * 100 + k];
    else if (k < 120) v = te[tag[bt] * 20 + (k - 100)];
    else if (k < 140) v = p1e[pos1[bt] * 20 + (k - 120)];
    else              v = p2e[pos2[bt] * 20 + (k - 140)];
    emb[idx] = v;
}

// ---------------------------------------------------------------------------
// Phase 1: input-gate GEMM.
// xg layout: [dir][t][bpair(64)][gj(1024)][2]  (b = bpair*2 + c)
// so the scan's per-step gate load is a coalesced dwordx2 over lanes=hid.
// ---------------------------------------------------------------------------
__global__ void __launch_bounds__(256) gemm_xg(
    const float* __restrict__ emb,
    const float* __restrict__ wihf, const float* __restrict__ bihf, const float* __restrict__ bhhf,
    const float* __restrict__ wihb, const float* __restrict__ bihb, const float* __restrict__ bhhb,
    float* __restrict__ xg)
{
    int gt  = blockIdx.x;
    int t   = blockIdx.y;
    int dir = blockIdx.z;
    const float* w  = dir ? wihb : wihf;
    const float* bi = dir ? bihb : bihf;
    const float* bh = dir ? bhhb : bhhf;
    int gj0 = gt * 128;

    __shared__ float wsh[32][132];   // [k][gj], padded
    __shared__ float esh[32][132];   // [k][b],  padded

    int tid = threadIdx.x;
    int tx = tid & 15, ty = tid >> 4;

    float acc[8][8];
    #pragma unroll
    for (int i = 0; i < 8; ++i)
        #pragma unroll
        for (int j = 0; j < 8; ++j) acc[i][j] = 0.f;

    for (int k0 = 0; k0 < IND_; k0 += 32) {
        __syncthreads();
        #pragma unroll
        for (int m = 0; m < 16; ++m) {
            int e = m * 256 + tid;        // 0..4095
            int k = e & 31, g = e >> 5;   // g: row (gj or b)
            wsh[k][g] = w[(gj0 + g) * IND_ + k0 + k];
            esh[k][g] = emb[(g * L_ + t) * IND_ + k0 + k];
        }
        __syncthreads();
        #pragma unroll
        for (int k = 0; k < 32; ++k) {
            float wv[8], ev[8];
            #pragma unroll
            for (int q = 0; q < 8; ++q) wv[q] = wsh[k][ty * 8 + q];
            #pragma unroll
            for (int q = 0; q < 8; ++q) ev[q] = esh[k][tx * 8 + q];
            #pragma unroll
            for (int i = 0; i < 8; ++i)
                #pragma unroll
                for (int j = 0; j < 8; ++j) acc[i][j] = fmaf(wv[i], ev[j], acc[i][j]);
        }
    }
    #pragma unroll
    for (int i = 0; i < 8; ++i) {
        int gj = gj0 + ty * 8 + i;
        float bias = bi[gj] + bh[gj];
        #pragma unroll
        for (int j = 0; j < 8; ++j) {
            int b = tx * 8 + j;
            xg[((((size_t)dir * L_ + t) * 64 + (b >> 1)) * 1024 + gj) * 2 + (b & 1)]
                = acc[i][j] + bias;
        }
    }
}

// ---------------------------------------------------------------------------
// Phase 1.5: pack recurrent weights to f16x2.
// wp16[dir][p(128)][hid(256)][gate(4)] : uint = {f16(w[g][hid][2p]), f16(w[g][hid][2p+1])}
// ---------------------------------------------------------------------------
__global__ void whh_pack16(const float* __restrict__ whhf, const float* __restrict__ whhb,
                           unsigned* __restrict__ wp)
{
    int gid = blockIdx.x * 256 + threadIdx.x;   // exactly 2*128*256*4 threads
    int g   = gid & 3;
    int h   = (gid >> 2) & 255;
    int p   = (gid >> 10) & 127;
    int dir = gid >> 17;
    const float* whh = dir ? whhb : whhf;
    const float* row = whh + (size_t)(g * 256 + h) * HID_;
    wp[gid] = pack2(row[2 * p], row[2 * p + 1]);
}

// ---------------------------------------------------------------------------
// Phase 2: BiLSTM scan with CU-RESIDENT weights. 128 blocks x 256 threads,
// 1 block/CU (84KB LDS enforces it). Per thread (one hidden unit, 4 gates,
// 2 batch cols) the 128 k-pair weight slices split:
//   p 0..63   -> 64 uint4 pinned in VGPRs (statically indexed, loaded once)
//   p 64..83  -> LDS (80KB, staged once, conflict-free b128 reads)
//   p 84..127 -> streamed from L2 (176KB/step/CU, was 512KB = the bound)
// Per-step pipe model: VMEM ~1.6us, LDS ~1.7us, VALU ~0.85us -> ~2.0-2.6us.
// ---------------------------------------------------------------------------
__global__ void __launch_bounds__(256, 1) lstm_scan_r(
    const float* __restrict__ xg, const uint4* __restrict__ wp16,
    float* __restrict__ xf2, float* __restrict__ xb2)
{
    int blk = blockIdx.x;
    int dir = blk >> 6;            // 0..1
    int bp  = blk & 63;            // b-pair index
    int h   = threadIdx.x;         // hidden unit 0..255

    const uint4* wt = wp16 + (size_t)dir * 128 * 256;   // [p][hid] uint4
    float* xo = dir ? xb2 : xf2;

    __shared__ uint2 hA[128];            // [p] = {bs0 f16x2, bs1 f16x2}
    __shared__ uint2 hB[128];
    __shared__ uint4 wlds[NLDS][256];    // p = NREG..NREG+NLDS-1, 80KB

    // stage LDS-resident weight slices (coalesced, once)
    for (int m = 0; m < NLDS; ++m)
        wlds[m][h] = wt[(NREG + m) * 256 + h];

    // pin p=0..NREG-1 in registers (static indices only -> stays in VGPRs)
    uint4 wr[NREG];
    #pragma unroll
    for (int p = 0; p < NREG; ++p) wr[p] = wt[p * 256 + h];

    ((unsigned*)hA)[h] = 0u;    // zero all 256 words of hA
    float c0 = 0.f, c1 = 0.f;
    __syncthreads();

    for (int t = 0; t < L_; ++t) {
        int slot = dir ? (L_ - 1 - t) : t;
        const uint2* hp = (t & 1) ? hB : hA;
        unsigned*    hw = (unsigned*)((t & 1) ? hA : hB);

        // xg gate preloads (fp32, exact; consumed in epilogue)
        const float* xbase = xg + (((size_t)dir * L_ + slot) * 64 + bp) * 2048;
        float2 gI = *(const float2*)(xbase + (0 * 256 + h) * 2);
        float2 gF = *(const float2*)(xbase + (1 * 256 + h) * 2);
        float2 gG = *(const float2*)(xbase + (2 * 256 + h) * 2);
        float2 gO = *(const float2*)(xbase + (3 * 256 + h) * 2);

        float aI0 = 0.f, aI1 = 0.f, aF0 = 0.f, aF1 = 0.f;
        float aG0 = 0.f, aG1 = 0.f, aO0 = 0.f, aO1 = 0.f;

        // --- streamed slices first: loads issue early, later phases hide them
        #pragma unroll
        for (int ps = 0; ps < NSTRM; ++ps) {
            uint4 w4 = wt[(PSTRM + ps) * 256 + h];   // coalesced 1KB/wave from L2
            uint2 hb = hp[PSTRM + ps];
            aI0 = fdot2_(w4.x, hb.x, aI0); aI1 = fdot2_(w4.x, hb.y, aI1);
            aF0 = fdot2_(w4.y, hb.x, aF0); aF1 = fdot2_(w4.y, hb.y, aF1);
            aG0 = fdot2_(w4.z, hb.x, aG0); aG1 = fdot2_(w4.z, hb.y, aG1);
            aO0 = fdot2_(w4.w, hb.x, aO0); aO1 = fdot2_(w4.w, hb.y, aO1);
        }
        // --- register-resident slices (pure VALU, no memory)
        #pragma unroll
        for (int p = 0; p < NREG; ++p) {
            uint2 hb = hp[p];
            aI0 = fdot2_(wr[p].x, hb.x, aI0); aI1 = fdot2_(wr[p].x, hb.y, aI1);
            aF0 = fdot2_(wr[p].y, hb.x, aF0); aF1 = fdot2_(wr[p].y, hb.y, aF1);
            aG0 = fdot2_(wr[p].z, hb.x, aG0); aG1 = fdot2_(wr[p].z, hb.y, aG1);
            aO0 = fdot2_(wr[p].w, hb.x, aO0); aO1 = fdot2_(wr[p].w, hb.y, aO1);
        }
        // --- LDS-resident slices
        #pragma unroll
        for (int p = 0; p < NLDS; ++p) {
            uint4 w4 = wlds[p][h];                   // conflict-free b128
            uint2 hb = hp[NREG + p];
            aI0 = fdot2_(w4.x, hb.x, aI0); aI1 = fdot2_(w4.x, hb.y, aI1);
            aF0 = fdot2_(w4.y, hb.x, aF0); aF1 = fdot2_(w4.y, hb.y, aF1);
            aG0 = fdot2_(w4.z, hb.x, aG0); aG1 = fdot2_(w4.z, hb.y, aG1);
            aO0 = fdot2_(w4.w, hb.x, aO0); aO1 = fdot2_(w4.w, hb.y, aO1);
        }

        // thread-local gate coupling (fp32 exact on the xg side)
        float i0 = 1.f / (1.f + expf(-(aI0 + gI.x)));
        float f0 = 1.f / (1.f + expf(-(aF0 + gF.x)));
        float g0 = tanhf(aG0 + gG.x);
        float o0 = 1.f / (1.f + expf(-(aO0 + gO.x)));
        c0 = f0 * c0 + i0 * g0;
        float hv0 = o0 * tanhf(c0);

        float i1 = 1.f / (1.f + expf(-(aI1 + gI.y)));
        float f1 = 1.f / (1.f + expf(-(aF1 + gF.y)));
        float g1 = tanhf(aG1 + gG.y);
        float o1 = 1.f / (1.f + expf(-(aO1 + gO.y)));
        c1 = f1 * c1 + i1 * g1;
        float hv1 = o1 * tanhf(c1);

        // pack h to f16x2 pairs: thread 2p and 2p+1 exchange via shfl_xor(1)
        float n0 = __shfl_xor(hv0, 1);
        float n1 = __shfl_xor(hv1, 1);
        hw[h] = (h & 1) ? pack2(n1, hv1)    // odd h -> slot [p][bs1]
                        : pack2(hv0, n0);   // even h -> slot [p][bs0]
        // f32 output, block-friendly layout [slot][bp][hid*2+bs] (coalesced)
        float* xp = xo + ((size_t)slot * 64 + bp) * 512 + h * 2;
        xp[0] = hv0; xp[1] = hv1;
        __syncthreads();   // hw visible before next step's reads
    }
}

// remap [slot][bp][hid*2+bs] -> x[slot][hid][b], summing directions.
// Index mapping chosen so WRITES are lane-contiguous (scatter moved to the
// read side, where L2/L3 absorb it; scattered 8B writes caused HBM RMW).
__global__ void x_add(const float* __restrict__ xf2, const float* __restrict__ xb2,
                      float* __restrict__ x)
{
    int idx = blockIdx.x * 256 + threadIdx.x;   // exactly L_*HID_*B_ threads
    int b    = idx & 127;
    int j    = (idx >> 7) & 255;
    int slot = idx >> 15;
    int src  = ((slot * 64 + (b >> 1)) * 512) + j * 2 + (b & 1);
    x[idx] = xf2[src] + xb2[src];
}

// ---------------------------------------------------------------------------
// Phase 3: entity features, attention, primary capsules
// ---------------------------------------------------------------------------
__global__ void find_entity(const int* __restrict__ pos1, const int* __restrict__ pos2,
                            int* __restrict__ e)
{
    int b = threadIdx.x;
    int e1 = 0, e2 = 0;
    for (int l = L_ - 1; l >= 0; --l) if (pos1[b * L_ + l] == ENTITY) e1 = l;
    for (int l = L_ - 1; l >= 0; --l) if (pos2[b * L_ + l] == ENTITY) e2 = l;
    e[b] = e1; e[B_ + b] = e2;
}

__global__ void compute_he(const float* __restrict__ x, const int* __restrict__ e,
                           float* __restrict__ he)
{
    int j = blockIdx.x, b = threadIdx.x;
    int e1 = e[b], e2 = e[B_ + b];
    he[j * B_ + b] = x[((size_t)e1 * HID_ + j) * B_ + b] + x[((size_t)e2 * HID_ + j) * B_ + b];
}

__global__ void att_logits(const float* __restrict__ x, const float* __restrict__ he,
                           float* __restrict__ logits)
{
    int l = blockIdx.x, b = threadIdx.x;
    float acc = 0.f;
    for (int j = 0; j < HID_; ++j)
        acc = fmaf(x[((size_t)l * HID_ + j) * B_ + b], he[j * B_ + b], acc);
    logits[l * B_ + b] = acc;
}

__global__ void att_softmax(const float* __restrict__ logits, float* __restrict__ att)
{
    int b = threadIdx.x;
    float m = -1e30f;
    for (int l = 0; l < L_; ++l) m = fmaxf(m, logits[l * B_ + b]);
    float s = 0.f;
    for (int l = 0; l < L_; ++l) s += expf(logits[l * B_ + b] - m);
    float inv = 1.f / s;
    for (int l = 0; l < L_; ++l) att[l * B_ + b] = expf(logits[l * B_ + b] - m) * inv;
}

// primary capsules: u[i][b][c], squashed
__global__ void u_squash(const float* __restrict__ x, float* __restrict__ u)
{
    int i = blockIdx.x, b = threadIdx.x;
    int l = i >> 4, cap = i & 15;
    float vals[16]; float n2 = 0.f;
    #pragma unroll
    for (int c2 = 0; c2 < 16; ++c2) {
        float v = x[((size_t)l * HID_ + cap * 16 + c2) * B_ + b];
        vals[c2] = v; n2 = fmaf(v, v, n2);
    }
    float f = (n2 / (1.f + n2)) / sqrtf(n2 + 1e-9f);
    #pragma unroll
    for (int c2 = 0; c2 < 16; ++c2)
        u[((size_t)i * B_ + b) * 16 + c2] = vals[c2] * f;
}

// ---------------------------------------------------------------------------
// Phase 4: routing
// ---------------------------------------------------------------------------
__global__ void bb_init(const float* __restrict__ br, float* __restrict__ bb)
{
    int idx = blockIdx.x * 256 + threadIdx.x;   // exactly B_*NI*NCLASS threads
    bb[idx] = br[idx % (NI * NCLASS)];
}

__global__ void __launch_bounds__(320) s_pass(
    const float* __restrict__ u, const float* __restrict__ W,
    const float* __restrict__ bb, const float* __restrict__ att,
    float* __restrict__ partial)
{
    int ic = blockIdx.x, bt = blockIdx.y;
    int i0 = ic * 16, b0 = bt * 16;
    __shared__ float C[16][16][20];   // [bl][il][o], padded
    int tid = threadIdx.x;
    if (tid < 256) {
        int bl = tid >> 4, il = tid & 15;
        int b = b0 + bl, i = i0 + il;
        const float* bbp = bb + ((size_t)b * NI + i) * NCLASS;
        float m = bbp[0];
        #pragma unroll
        for (int o = 1; o < NCLASS; ++o) m = fmaxf(m, bbp[o]);
        float s = 0.f; float e[NCLASS];
        #pragma unroll
        for (int o = 0; o < NCLASS; ++o) { e[o] = expf(bbp[o] - m); s += e[o]; }
        float al = att[(i >> 4) * B_ + b] / s;
        #pragma unroll
        for (int o = 0; o < NCLASS; ++o) C[bl][il][o] = e[o] * al;
    }
    __syncthreads();
    if (tid >= OD) return;
    int od = tid, o = od >> 4;
    float acc[16];
    #pragma unroll
    for (int bl = 0; bl < 16; ++bl) acc[bl] = 0.f;
    for (int il = 0; il < 16; ++il) {
        int i = i0 + il;
        const float* wp = W + (size_t)i * 16 * OD + od;
        float w[16];
        #pragma unroll
        for (int c2 = 0; c2 < 16; ++c2) w[c2] = wp[c2 * OD];     // coalesced over od
        const float* up = u + ((size_t)i * B_ + b0) * 16;        // uniform -> s_load
        #pragma unroll
        for (int bl = 0; bl < 16; ++bl) {
            float uh = 0.f;
            #pragma unroll
            for (int c2 = 0; c2 < 16; ++c2) uh = fmaf(up[bl * 16 + c2], w[c2], uh);
            acc[bl] = fmaf(C[bl][il][o], uh, acc[bl]);
        }
    }
    #pragma unroll
    for (int bl = 0; bl < 16; ++bl)
        partial[((size_t)ic * B_ + b0 + bl) * OD + od] = acc[bl];
}

__global__ void s_reduce(const float* __restrict__ partial, float* __restrict__ s)
{
    int idx = blockIdx.x * 256 + threadIdx.x;   // exactly B_*OD threads
    int b = idx / OD, od = idx - b * OD;
    float acc = 0.f;
    for (int ic = 0; ic < 100; ++ic) acc += partial[((size_t)ic * B_ + b) * OD + od];
    s[idx] = acc;
}

__global__ void squash_v(const float* __restrict__ s, float* __restrict__ v,
                         float* __restrict__ out, int write_out)
{
    int idx = blockIdx.x * 256 + threadIdx.x;
    if (idx >= B_ * NCLASS) return;
    const float* sp = s + (size_t)idx * 16;     // b*304 + o*16 == idx*16
    float vals[16]; float n2 = 0.f;
    #pragma unroll
    for (int d = 0; d < 16; ++d) { vals[d] = sp[d]; n2 = fmaf(vals[d], vals[d], n2); }
    float f = (n2 / (1.f + n2)) / sqrtf(n2 + 1e-9f);
    float n2v = 0.f;
    #pragma unroll
    for (int d = 0; d < 16; ++d) {
        float vv = vals[d] * f;
        v[(size_t)idx * 16 + d] = vv;
        n2v = fmaf(vv, vv, n2v);
    }
    if (write_out) out[idx] = sqrtf(n2v + 1e-9f);
}

__global__ void __launch_bounds__(320) bb_pass(
    const float* __restrict__ u, const float* __restrict__ W,
    const float* __restrict__ v, float* __restrict__ bb)
{
    int ic = blockIdx.x, bt = blockIdx.y;
    int i0 = ic * 16, b0 = bt * 16;
    int tid = threadIdx.x;
    if (tid >= OD) return;
    int od = tid, o = od >> 4, d = od & 15;
    float vv[16];
    #pragma unroll
    for (int bl = 0; bl < 16; ++bl) vv[bl] = v[(size_t)(b0 + bl) * OD + od];
    for (int il = 0; il < 16; ++il) {
        int i = i0 + il;
        const float* wp = W + (size_t)i * 16 * OD + od;
        float w[16];
        #pragma unroll
        for (int c2 = 0; c2 < 16; ++c2) w[c2] = wp[c2 * OD];
        const float* up = u + ((size_t)i * B_ + b0) * 16;
        #pragma unroll
        for (int bl = 0; bl < 16; ++bl) {
            float uh = 0.f;
            #pragma unroll
            for (int c2 = 0; c2 < 16; ++c2) uh = fmaf(up[bl * 16 + c2], w[c2], uh);
            float p = uh * vv[bl];
            p += __shfl_xor(p, 1);
            p += __shfl_xor(p, 2);
            p += __shfl_xor(p, 4);
            p += __shfl_xor(p, 8);
            if (d == 0) bb[((size_t)(b0 + bl) * NI + i) * NCLASS + o] += p;
        }
    }
}

// ---------------------------------------------------------------------------
extern "C" void kernel_launch(void* const* d_in, const int* in_sizes, int n_in,
                              void* d_out, int out_size, void* d_ws, size_t ws_size,
                              hipStream_t stream)
{
    (void)in_sizes; (void)n_in; (void)out_size; (void)ws_size;
    const int*   word = (const int*)d_in[0];
    const int*   tag  = (const int*)d_in[1];
    const int*   pos1 = (const int*)d_in[2];
    const int*   pos2 = (const int*)d_in[3];
    const float* we   = (const float*)d_in[4];
    const float* te   = (const float*)d_in[5];
    const float* p1e  = (const float*)d_in[6];
    const float* p2e  = (const float*)d_in[7];
    const float* wihf = (const float*)d_in[8];
    const float* whhf = (const float*)d_in[9];
    const float* bihf = (const float*)d_in[10];
    const float* bhhf = (const float*)d_in[11];
    const float* wihb = (const float*)d_in[12];
    const float* whhb = (const float*)d_in[13];
    const float* bihb = (const float*)d_in[14];
    const float* bhhb = (const float*)d_in[15];
    const float* Wc   = (const float*)d_in[16];
    const float* br   = (const float*)d_in[17];

    float* wsp    = (float*)d_ws;
    float* emb    = wsp;                       //  2,048,000
    float* xg     = wsp + 2048000;             // 26,214,400
    float* xf     = xg + 26214400;             //  3,276,800
    float* xb     = xf + 3276800;              //  3,276,800
    float* he     = xb + 3276800;              //     32,768
    float* logits = he + 32768;                //     12,800
    float* att    = logits + 12800;            //     12,800
    int*   e      = (int*)(att + 12800);       //        256 ints
    // packed f16 recurrent weights alias the (dead-after-gemm_xg) emb region
    unsigned* wp16 = (unsigned*)emb;           //  262,144 uints (1 MB)
    // post-scan buffers alias the (dead-after-scan) xg region
    float* x    = xg;                          //  3,276,800
    float* u    = xg + 3276800;                //  3,276,800
    float* bb   = xg + 6553600;                //  3,891,200
    float* part = xg + 10444800;               //  3,891,200
    float* s    = xg + 14336000;               //     38,912
    float* v    = s + 38912;                   //     38,912
    float* out  = (float*)d_out;

    emb_gather<<<8000, 256, 0, stream>>>(word, tag, pos1, pos2, we, te, p1e, p2e, emb);
    gemm_xg<<<dim3(8, 100, 2), 256, 0, stream>>>(emb, wihf, bihf, bhhf, wihb, bihb, bhhb, xg);
    whh_pack16<<<1024, 256, 0, stream>>>(whhf, whhb, wp16);
    lstm_scan_r<<<128, 256, 0, stream>>>(xg, (const uint4*)wp16, xf, xb);
    x_add<<<12800, 256, 0, stream>>>(xf, xb, x);
    find_entity<<<1, 128, 0, stream>>>(pos1, pos2, e);
    compute_he<<<256, 128, 0, stream>>>(x, e, he);
    att_logits<<<100, 128, 0, stream>>>(x, he, logits);
    att_softmax<<<1, 128, 0, stream>>>(logits, att);
    u_squash<<<1600, 128, 0, stream>>>(x, u);
    bb_init<<<15200, 256, 0, stream>>>(br, bb);
    for (int it = 0; it < 3; ++it) {
        s_pass<<<dim3(100, 8), 320, 0, stream>>>(u, Wc, bb, att, part);
        s_reduce<<<152, 256, 0, stream>>>(part, s);
        squash_v<<<10, 256, 0, stream>>>(s, v, out, (it == 2) ? 1 : 0);
        if (it < 2) bb_pass<<<dim3(100, 8), 320, 0, stream>>>(u, Wc, v, bb);
    }
}

// Round 6
// 1518.570 us; speedup vs baseline: 13.4947x; 13.4947x over previous
//
#include <hip/hip_runtime.h>
#include <math.h>

#define B_     128
#define L_     100
#define HID_   256
#define IND_   160
#define NCLASS 19
#define CAPD   16
#define NI     1600      // L_ * NUM_CAPS
#define OD     304       // NCLASS * CAPD
#define ENTITY 68

// scan weight partition (of 128 k-pair slices): register / LDS / streamed
// HW constraint (R5 lesson): non-MFMA code addresses only 256 VGPRs ->
// register tier must stay ~<=24 uint4 (96 VGPRs) to avoid scratch spill.
#define NREG   24
#define NLDS   32
#define PSTRM  (NREG + NLDS)     // 56
#define NSTRM  (128 - PSTRM)     // 72

typedef _Float16 half2_t __attribute__((ext_vector_type(2)));

__device__ inline half2_t as_h2(unsigned u) {
    union { unsigned u; half2_t h; } x; x.u = u; return x.h;
}
__device__ inline unsigned pack2(float a, float b) {
    union { unsigned u; half2_t h; } x;
    x.h = (half2_t){ (_Float16)a, (_Float16)b };   // RTN converts
    return x.u;
}
__device__ inline float fdot2_(unsigned w, unsigned h, float acc) {
#if __has_builtin(__builtin_amdgcn_fdot2)
    return __builtin_amdgcn_fdot2(as_h2(w), as_h2(h), acc, false);
#else
    half2_t wh = as_h2(w), hh = as_h2(h);
    acc = fmaf((float)wh.x, (float)hh.x, acc);
    return fmaf((float)wh.y, (float)hh.y, acc);
#endif
}

// ---------------------------------------------------------------------------
// Phase 0: embedding gather -> emb [b*L_+t][160]
// ---------------------------------------------------------------------------
__global__ void emb_gather(const int* __restrict__ word, const int* __restrict__ tag,
                           const int* __restrict__ pos1, const int* __restrict__ pos2,
                           const float* __restrict__ we, const float* __restrict__ te,
                           const float* __restrict__ p1e, const float* __restrict__ p2e,
                           float* __restrict__ emb)
{
    int idx = blockIdx.x * 256 + threadIdx.x;          // exactly B_*L_*IND_ threads
    int bt = idx / IND_;
    int k  = idx - bt * IND_;
    float v;
    if (k < 100)      v = we[word[bt] * 100 + k];
    else if (k < 120) v = te[tag[bt] * 20 + (k - 100)];
    else if (k < 140) v = p1e[pos1[bt] * 20 + (k - 120)];
    else              v = p2e[pos2[bt] * 20 + (k - 140)];
    emb[idx] = v;
}

// ---------------------------------------------------------------------------
// Phase 1: input-gate GEMM.
// xg layout: [dir][t][bpair(64)][gj(1024)][2]  (b = bpair*2 + c)
// ---------------------------------------------------------------------------
__global__ void __launch_bounds__(256) gemm_xg(
    const float* __restrict__ emb,
    const float* __restrict__ wihf, const float* __restrict__ bihf, const float* __restrict__ bhhf,
    const float* __restrict__ wihb, const float* __restrict__ bihb, const float* __restrict__ bhhb,
    float* __restrict__ xg)
{
    int gt  = blockIdx.x;
    int t   = blockIdx.y;
    int dir = blockIdx.z;
    const float* w  = dir ? wihb : wihf;
    const float* bi = dir ? bihb : bihf;
    const float* bh = dir ? bhhb : bhhf;
    int gj0 = gt * 128;

    __shared__ float wsh[32][132];   // [k][gj], padded
    __shared__ float esh[32][132];   // [k][b],  padded

    int tid = threadIdx.x;
    int tx = tid & 15, ty = tid >> 4;

    float acc[8][8];
    #pragma unroll
    for (int i = 0; i < 8; ++i)
        #pragma unroll
        for (int j = 0; j < 8; ++j) acc[i][j] = 0.f;

    for (int k0 = 0; k0 < IND_; k0 += 32) {
        __syncthreads();
        #pragma unroll
        for (int m = 0; m < 16; ++m) {
            int e = m * 256 + tid;        // 0..4095
            int k = e & 31, g = e >> 5;   // g: row (gj or b)
            wsh[k][g] = w[(gj0 + g) * IND_ + k0 + k];
            esh[k][g] = emb[(g * L_ + t) * IND_ + k0 + k];
        }
        __syncthreads();
        #pragma unroll
        for (int k = 0; k < 32; ++k) {
            float wv[8], ev[8];
            #pragma unroll
            for (int q = 0; q < 8; ++q) wv[q] = wsh[k][ty * 8 + q];
            #pragma unroll
            for (int q = 0; q < 8; ++q) ev[q] = esh[k][tx * 8 + q];
            #pragma unroll
            for (int i = 0; i < 8; ++i)
                #pragma unroll
                for (int j = 0; j < 8; ++j) acc[i][j] = fmaf(wv[i], ev[j], acc[i][j]);
        }
    }
    #pragma unroll
    for (int i = 0; i < 8; ++i) {
        int gj = gj0 + ty * 8 + i;
        float bias = bi[gj] + bh[gj];
        #pragma unroll
        for (int j = 0; j < 8; ++j) {
            int b = tx * 8 + j;
            xg[((((size_t)dir * L_ + t) * 64 + (b >> 1)) * 1024 + gj) * 2 + (b & 1)]
                = acc[i][j] + bias;
        }
    }
}

// ---------------------------------------------------------------------------
// Phase 1.5: pack recurrent weights to f16x2.
// wp16[dir][p(128)][hid(256)][gate(4)] : uint = {f16(w[g][hid][2p]), f16(w[g][hid][2p+1])}
// ---------------------------------------------------------------------------
__global__ void whh_pack16(const float* __restrict__ whhf, const float* __restrict__ whhb,
                           unsigned* __restrict__ wp)
{
    int gid = blockIdx.x * 256 + threadIdx.x;   // exactly 2*128*256*4 threads
    int g   = gid & 3;
    int h   = (gid >> 2) & 255;
    int p   = (gid >> 10) & 127;
    int dir = gid >> 17;
    const float* whh = dir ? whhb : whhf;
    const float* row = whh + (size_t)(g * 256 + h) * HID_;
    wp[gid] = pack2(row[2 * p], row[2 * p + 1]);
}

// ---------------------------------------------------------------------------
// Phase 2: BiLSTM scan, partial CU-residency sized to the register file.
// 128 blocks x 256 threads, 1 block/CU (130KB LDS enforces).
//   p 0..23   -> 24 uint4 in VGPRs (96 regs; R5 proved 64 slices spills)
//   p 24..55  -> LDS (128KB, staged once)
//   p 56..127 -> streamed from L2: 288KB/step/CU (was 512KB @ 95GB/s/CU)
// Model/step: VMEM 3.0us, LDS ~1.9us, VALU 0.85us -> ~3.0-3.6us.
// ---------------------------------------------------------------------------
__global__ void __launch_bounds__(256, 1) lstm_scan_r2(
    const float* __restrict__ xg, const uint4* __restrict__ wp16,
    float* __restrict__ xf2, float* __restrict__ xb2)
{
    int blk = blockIdx.x;
    int dir = blk >> 6;            // 0..1
    int bp  = blk & 63;            // b-pair index
    int h   = threadIdx.x;         // hidden unit 0..255

    const uint4* wt = wp16 + (size_t)dir * 128 * 256;   // [p][hid] uint4
    float* xo = dir ? xb2 : xf2;

    __shared__ uint2 hA[128];            // [p] = {bs0 f16x2, bs1 f16x2}
    __shared__ uint2 hB[128];
    __shared__ uint4 wlds[NLDS][256];    // p = NREG..PSTRM-1, 128KB

    // stage LDS-resident weight slices (coalesced, once)
    for (int m = 0; m < NLDS; ++m)
        wlds[m][h] = wt[(NREG + m) * 256 + h];

    // pin p=0..NREG-1 in registers (static indices -> stays in VGPRs)
    uint4 wr[NREG];
    #pragma unroll
    for (int p = 0; p < NREG; ++p) wr[p] = wt[p * 256 + h];

    ((unsigned*)hA)[h] = 0u;    // zero all 256 words of hA
    float c0 = 0.f, c1 = 0.f;
    __syncthreads();

    for (int t = 0; t < L_; ++t) {
        int slot = dir ? (L_ - 1 - t) : t;
        const uint2* hp = (t & 1) ? hB : hA;
        unsigned*    hw = (unsigned*)((t & 1) ? hA : hB);

        // xg gate preloads (fp32, exact; consumed in epilogue)
        const float* xbase = xg + (((size_t)dir * L_ + slot) * 64 + bp) * 2048;
        float2 gI = *(const float2*)(xbase + (0 * 256 + h) * 2);
        float2 gF = *(const float2*)(xbase + (1 * 256 + h) * 2);
        float2 gG = *(const float2*)(xbase + (2 * 256 + h) * 2);
        float2 gO = *(const float2*)(xbase + (3 * 256 + h) * 2);

        float aI0 = 0.f, aI1 = 0.f, aF0 = 0.f, aF1 = 0.f;
        float aG0 = 0.f, aG1 = 0.f, aO0 = 0.f, aO1 = 0.f;

        // --- streamed slices first: loads issue early, later phases hide them
        #pragma unroll 8
        for (int ps = 0; ps < NSTRM; ++ps) {
            uint4 w4 = wt[(PSTRM + ps) * 256 + h];   // coalesced 1KB/wave from L2
            uint2 hb = hp[PSTRM + ps];
            aI0 = fdot2_(w4.x, hb.x, aI0); aI1 = fdot2_(w4.x, hb.y, aI1);
            aF0 = fdot2_(w4.y, hb.x, aF0); aF1 = fdot2_(w4.y, hb.y, aF1);
            aG0 = fdot2_(w4.z, hb.x, aG0); aG1 = fdot2_(w4.z, hb.y, aG1);
            aO0 = fdot2_(w4.w, hb.x, aO0); aO1 = fdot2_(w4.w, hb.y, aO1);
        }
        // --- register-resident slices (pure VALU, no memory)
        #pragma unroll
        for (int p = 0; p < NREG; ++p) {
            uint2 hb = hp[p];
            aI0 = fdot2_(wr[p].x, hb.x, aI0); aI1 = fdot2_(wr[p].x, hb.y, aI1);
            aF0 = fdot2_(wr[p].y, hb.x, aF0); aF1 = fdot2_(wr[p].y, hb.y, aF1);
            aG0 = fdot2_(wr[p].z, hb.x, aG0); aG1 = fdot2_(wr[p].z, hb.y, aG1);
            aO0 = fdot2_(wr[p].w, hb.x, aO0); aO1 = fdot2_(wr[p].w, hb.y, aO1);
        }
        // --- LDS-resident slices
        #pragma unroll 8
        for (int p = 0; p < NLDS; ++p) {
            uint4 w4 = wlds[p][h];                   // conflict-free b128
            uint2 hb = hp[NREG + p];
            aI0 = fdot2_(w4.x, hb.x, aI0); aI1 = fdot2_(w4.x, hb.y, aI1);
            aF0 = fdot2_(w4.y, hb.x, aF0); aF1 = fdot2_(w4.y, hb.y, aF1);
            aG0 = fdot2_(w4.z, hb.x, aG0); aG1 = fdot2_(w4.z, hb.y, aG1);
            aO0 = fdot2_(w4.w, hb.x, aO0); aO1 = fdot2_(w4.w, hb.y, aO1);
        }

        // thread-local gate coupling (fp32 exact on the xg side)
        float i0 = 1.f / (1.f + expf(-(aI0 + gI.x)));
        float f0 = 1.f / (1.f + expf(-(aF0 + gF.x)));
        float g0 = tanhf(aG0 + gG.x);
        float o0 = 1.f / (1.f + expf(-(aO0 + gO.x)));
        c0 = f0 * c0 + i0 * g0;
        float hv0 = o0 * tanhf(c0);

        float i1 = 1.f / (1.f + expf(-(aI1 + gI.y)));
        float f1 = 1.f / (1.f + expf(-(aF1 + gF.y)));
        float g1 = tanhf(aG1 + gG.y);
        float o1 = 1.f / (1.f + expf(-(aO1 + gO.y)));
        c1 = f1 * c1 + i1 * g1;
        float hv1 = o1 * tanhf(c1);

        // pack h to f16x2 pairs: thread 2p and 2p+1 exchange via shfl_xor(1)
        float n0 = __shfl_xor(hv0, 1);
        float n1 = __shfl_xor(hv1, 1);
        hw[h] = (h & 1) ? pack2(n1, hv1)    // odd h -> slot [p][bs1]
                        : pack2(hv0, n0);   // even h -> slot [p][bs0]
        // f32 output, block-friendly layout [slot][bp][hid*2+bs] (coalesced)
        float* xp = xo + ((size_t)slot * 64 + bp) * 512 + h * 2;
        xp[0] = hv0; xp[1] = hv1;
        __syncthreads();   // hw visible before next step's reads
    }
}

// remap [slot][bp][hid*2+bs] -> x[slot][hid][b], summing directions.
// Writes lane-contiguous; scatter on the read side (L2/L3 absorbs).
__global__ void x_add(const float* __restrict__ xf2, const float* __restrict__ xb2,
                      float* __restrict__ x)
{
    int idx = blockIdx.x * 256 + threadIdx.x;   // exactly L_*HID_*B_ threads
    int b    = idx & 127;
    int j    = (idx >> 7) & 255;
    int slot = idx >> 15;
    int src  = ((slot * 64 + (b >> 1)) * 512) + j * 2 + (b & 1);
    x[idx] = xf2[src] + xb2[src];
}

// ---------------------------------------------------------------------------
// Phase 3: entity features, attention, primary capsules
// ---------------------------------------------------------------------------
__global__ void find_entity(const int* __restrict__ pos1, const int* __restrict__ pos2,
                            int* __restrict__ e)
{
    int b = threadIdx.x;
    int e1 = 0, e2 = 0;
    for (int l = L_ - 1; l >= 0; --l) if (pos1[b * L_ + l] == ENTITY) e1 = l;
    for (int l = L_ - 1; l >= 0; --l) if (pos2[b * L_ + l] == ENTITY) e2 = l;
    e[b] = e1; e[B_ + b] = e2;
}

__global__ void compute_he(const float* __restrict__ x, const int* __restrict__ e,
                           float* __restrict__ he)
{
    int j = blockIdx.x, b = threadIdx.x;
    int e1 = e[b], e2 = e[B_ + b];
    he[j * B_ + b] = x[((size_t)e1 * HID_ + j) * B_ + b] + x[((size_t)e2 * HID_ + j) * B_ + b];
}

__global__ void att_logits(const float* __restrict__ x, const float* __restrict__ he,
                           float* __restrict__ logits)
{
    int l = blockIdx.x, b = threadIdx.x;
    float acc = 0.f;
    for (int j = 0; j < HID_; ++j)
        acc = fmaf(x[((size_t)l * HID_ + j) * B_ + b], he[j * B_ + b], acc);
    logits[l * B_ + b] = acc;
}

__global__ void att_softmax(const float* __restrict__ logits, float* __restrict__ att)
{
    int b = threadIdx.x;
    float m = -1e30f;
    for (int l = 0; l < L_; ++l) m = fmaxf(m, logits[l * B_ + b]);
    float s = 0.f;
    for (int l = 0; l < L_; ++l) s += expf(logits[l * B_ + b] - m);
    float inv = 1.f / s;
    for (int l = 0; l < L_; ++l) att[l * B_ + b] = expf(logits[l * B_ + b] - m) * inv;
}

// primary capsules: u[i][b][c], squashed
__global__ void u_squash(const float* __restrict__ x, float* __restrict__ u)
{
    int i = blockIdx.x, b = threadIdx.x;
    int l = i >> 4, cap = i & 15;
    float vals[16]; float n2 = 0.f;
    #pragma unroll
    for (int c2 = 0; c2 < 16; ++c2) {
        float v = x[((size_t)l * HID_ + cap * 16 + c2) * B_ + b];
        vals[c2] = v; n2 = fmaf(v, v, n2);
    }
    float f = (n2 / (1.f + n2)) / sqrtf(n2 + 1e-9f);
    #pragma unroll
    for (int c2 = 0; c2 < 16; ++c2)
        u[((size_t)i * B_ + b) * 16 + c2] = vals[c2] * f;
}

// ---------------------------------------------------------------------------
// Phase 4: routing
// ---------------------------------------------------------------------------
__global__ void bb_init(const float* __restrict__ br, float* __restrict__ bb)
{
    int idx = blockIdx.x * 256 + threadIdx.x;   // exactly B_*NI*NCLASS threads
    bb[idx] = br[idx % (NI * NCLASS)];
}

__global__ void __launch_bounds__(320) s_pass(
    const float* __restrict__ u, const float* __restrict__ W,
    const float* __restrict__ bb, const float* __restrict__ att,
    float* __restrict__ partial)
{
    int ic = blockIdx.x, bt = blockIdx.y;
    int i0 = ic * 16, b0 = bt * 16;
    __shared__ float C[16][16][20];   // [bl][il][o], padded
    int tid = threadIdx.x;
    if (tid < 256) {
        int bl = tid >> 4, il = tid & 15;
        int b = b0 + bl, i = i0 + il;
        const float* bbp = bb + ((size_t)b * NI + i) * NCLASS;
        float m = bbp[0];
        #pragma unroll
        for (int o = 1; o < NCLASS; ++o) m = fmaxf(m, bbp[o]);
        float s = 0.f; float e[NCLASS];
        #pragma unroll
        for (int o = 0; o < NCLASS; ++o) { e[o] = expf(bbp[o] - m); s += e[o]; }
        float al = att[(i >> 4) * B_ + b] / s;
        #pragma unroll
        for (int o = 0; o < NCLASS; ++o) C[bl][il][o] = e[o] * al;
    }
    __syncthreads();
    if (tid >= OD) return;
    int od = tid, o = od >> 4;
    float acc[16];
    #pragma unroll
    for (int bl = 0; bl < 16; ++bl) acc[bl] = 0.f;
    for (int il = 0; il < 16; ++il) {
        int i = i0 + il;
        const float* wp = W + (size_t)i * 16 * OD + od;
        float w[16];
        #pragma unroll
        for (int c2 = 0; c2 < 16; ++c2) w[c2] = wp[c2 * OD];     // coalesced over od
        const float* up = u + ((size_t)i * B_ + b0) * 16;        // uniform -> s_load
        #pragma unroll
        for (int bl = 0; bl < 16; ++bl) {
            float uh = 0.f;
            #pragma unroll
            for (int c2 = 0; c2 < 16; ++c2) uh = fmaf(up[bl * 16 + c2], w[c2], uh);
            acc[bl] = fmaf(C[bl][il][o], uh, acc[bl]);
        }
    }
    #pragma unroll
    for (int bl = 0; bl < 16; ++bl)
        partial[((size_t)ic * B_ + b0 + bl) * OD + od] = acc[bl];
}

__global__ void s_reduce(const float* __restrict__ partial, float* __restrict__ s)
{
    int idx = blockIdx.x * 256 + threadIdx.x;   // exactly B_*OD threads
    int b = idx / OD, od = idx - b * OD;
    float acc = 0.f;
    for (int ic = 0; ic < 100; ++ic) acc += partial[((size_t)ic * B_ + b) * OD + od];
    s[idx] = acc;
}

__global__ void squash_v(const float* __restrict__ s, float* __restrict__ v,
                         float* __restrict__ out, int write_out)
{
    int idx = blockIdx.x * 256 + threadIdx.x;
    if (idx >= B_ * NCLASS) return;
    const float* sp = s + (size_t)idx * 16;     // b*304 + o*16 == idx*16
    float vals[16]; float n2 = 0.f;
    #pragma unroll
    for (int d = 0; d < 16; ++d) { vals[d] = sp[d]; n2 = fmaf(vals[d], vals[d], n2); }
    float f = (n2 / (1.f + n2)) / sqrtf(n2 + 1e-9f);
    float n2v = 0.f;
    #pragma unroll
    for (int d = 0; d < 16; ++d) {
        float vv = vals[d] * f;
        v[(size_t)idx * 16 + d] = vv;
        n2v = fmaf(vv, vv, n2v);
    }
    if (write_out) out[idx] = sqrtf(n2v + 1e-9f);
}

__global__ void __launch_bounds__(320) bb_pass(
    const float* __restrict__ u, const float* __restrict__ W,
    const float* __restrict__ v, float* __restrict__ bb)
{
    int ic = blockIdx.x, bt = blockIdx.y;
    int i0 = ic * 16, b0 = bt * 16;
    int tid = threadIdx.x;
    if (tid >= OD) return;
    int od = tid, o = od >> 4, d = od & 15;
    float vv[16];
    #pragma unroll
    for (int bl = 0; bl < 16; ++bl) vv[bl] = v[(size_t)(b0 + bl) * OD + od];
    for (int il = 0; il < 16; ++il) {
        int i = i0 + il;
        const float* wp = W + (size_t)i * 16 * OD + od;
        float w[16];
        #pragma unroll
        for (int c2 = 0; c2 < 16; ++c2) w[c2] = wp[c2 * OD];
        const float* up = u + ((size_t)i * B_ + b0) * 16;
        #pragma unroll
        for (int bl = 0; bl < 16; ++bl) {
            float uh = 0.f;
            #pragma unroll
            for (int c2 = 0; c2 < 16; ++c2) uh = fmaf(up[bl * 16 + c2], w[c2], uh);
            float p = uh * vv[bl];
            p += __shfl_xor(p, 1);
            p += __shfl_xor(p, 2);
            p += __shfl_xor(p, 4);
            p += __shfl_xor(p, 8);
            if (d == 0) bb[((size_t)(b0 + bl) * NI + i) * NCLASS + o] += p;
        }
    }
}

// ---------------------------------------------------------------------------
extern "C" void kernel_launch(void* const* d_in, const int* in_sizes, int n_in,
                              void* d_out, int out_size, void* d_ws, size_t ws_size,
                              hipStream_t stream)
{
    (void)in_sizes; (void)n_in; (void)out_size; (void)ws_size;
    const int*   word = (const int*)d_in[0];
    const int*   tag  = (const int*)d_in[1];
    const int*   pos1 = (const int*)d_in[2];
    const int*   pos2 = (const int*)d_in[3];
    const float* we   = (const float*)d_in[4];
    const float* te   = (const float*)d_in[5];
    const float* p1e  = (const float*)d_in[6];
    const float* p2e  = (const float*)d_in[7];
    const float* wihf = (const float*)d_in[8];
    const float* whhf = (const float*)d_in[9];
    const float* bihf = (const float*)d_in[10];
    const float* bhhf = (const float*)d_in[11];
    const float* wihb = (const float*)d_in[12];
    const float* whhb = (const float*)d_in[13];
    const float* bihb = (const float*)d_in[14];
    const float* bhhb = (const float*)d_in[15];
    const float* Wc   = (const float*)d_in[16];
    const float* br   = (const float*)d_in[17];

    float* wsp    = (float*)d_ws;
    float* emb    = wsp;                       //  2,048,000
    float* xg     = wsp + 2048000;             // 26,214,400
    float* xf     = xg + 26214400;             //  3,276,800
    float* xb     = xf + 3276800;              //  3,276,800
    float* he     = xb + 3276800;              //     32,768
    float* logits = he + 32768;                //     12,800
    float* att    = logits + 12800;            //     12,800
    int*   e      = (int*)(att + 12800);       //        256 ints
    // packed f16 recurrent weights alias the (dead-after-gemm_xg) emb region
    unsigned* wp16 = (unsigned*)emb;           //  262,144 uints (1 MB)
    // post-scan buffers alias the (dead-after-scan) xg region
    float* x    = xg;                          //  3,276,800
    float* u    = xg + 3276800;                //  3,276,800
    float* bb   = xg + 6553600;                //  3,891,200
    float* part = xg + 10444800;               //  3,891,200
    float* s    = xg + 14336000;               //     38,912
    float* v    = s + 38912;                   //     38,912
    float* out  = (float*)d_out;

    emb_gather<<<8000, 256, 0, stream>>>(word, tag, pos1, pos2, we, te, p1e, p2e, emb);
    gemm_xg<<<dim3(8, 100, 2), 256, 0, stream>>>(emb, wihf, bihf, bhhf, wihb, bihb, bhhb, xg);
    whh_pack16<<<1024, 256, 0, stream>>>(whhf, whhb, wp16);
    lstm_scan_r2<<<128, 256, 0, stream>>>(xg, (const uint4*)wp16, xf, xb);
    x_add<<<12800, 256, 0, stream>>>(xf, xb, x);
    find_entity<<<1, 128, 0, stream>>>(pos1, pos2, e);
    compute_he<<<256, 128, 0, stream>>>(x, e, he);
    att_logits<<<100, 128, 0, stream>>>(x, he, logits);
    att_softmax<<<1, 128, 0, stream>>>(logits, att);
    u_squash<<<1600, 128, 0, stream>>>(x, u);
    bb_init<<<15200, 256, 0, stream>>>(br, bb);
    for (int it = 0; it < 3; ++it) {
        s_pass<<<dim3(100, 8), 320, 0, stream>>>(u, Wc, bb, att, part);
        s_reduce<<<152, 256, 0, stream>>>(part, s);
        squash_v<<<10, 256, 0, stream>>>(s, v, out, (it == 2) ? 1 : 0);
        if (it < 2) bb_pass<<<dim3(100, 8), 320, 0, stream>>>(u, Wc, v, bb);
    }
}

// Round 7
// 1436.594 us; speedup vs baseline: 14.2647x; 1.0571x over previous
//
#include <hip/hip_runtime.h>
#include <math.h>

#define B_     128
#define L_     100
#define HID_   256
#define IND_   160
#define NCLASS 19
#define CAPD   16
#define NI     1600      // L_ * NUM_CAPS
#define OD     304       // NCLASS * CAPD
#define ENTITY 68

#define SLDS   24        // LDS-resident weight slices (q0's p=0..23), 96KB

typedef _Float16 half2_t __attribute__((ext_vector_type(2)));

__device__ inline half2_t as_h2(unsigned u) {
    union { unsigned u; half2_t h; } x; x.u = u; return x.h;
}
__device__ inline unsigned pack2(float a, float b) {
    union { unsigned u; half2_t h; } x;
    x.h = (half2_t){ (_Float16)a, (_Float16)b };   // RTN converts
    return x.u;
}
__device__ inline float fdot2_(unsigned w, unsigned h, float acc) {
#if __has_builtin(__builtin_amdgcn_fdot2)
    return __builtin_amdgcn_fdot2(as_h2(w), as_h2(h), acc, false);
#else
    half2_t wh = as_h2(w), hh = as_h2(h);
    acc = fmaf((float)wh.x, (float)hh.x, acc);
    return fmaf((float)wh.y, (float)hh.y, acc);
#endif
}

// ---------------------------------------------------------------------------
// Phase 0: embedding gather -> emb [b*L_+t][160]
// ---------------------------------------------------------------------------
__global__ void emb_gather(const int* __restrict__ word, const int* __restrict__ tag,
                           const int* __restrict__ pos1, const int* __restrict__ pos2,
                           const float* __restrict__ we, const float* __restrict__ te,
                           const float* __restrict__ p1e, const float* __restrict__ p2e,
                           float* __restrict__ emb)
{
    int idx = blockIdx.x * 256 + threadIdx.x;          // exactly B_*L_*IND_ threads
    int bt = idx / IND_;
    int k  = idx - bt * IND_;
    float v;
    if (k < 100)      v = we[word[bt] * 100 + k];
    else if (k < 120) v = te[tag[bt] * 20 + (k - 100)];
    else if (k < 140) v = p1e[pos1[bt] * 20 + (k - 120)];
    else              v = p2e[pos2[bt] * 20 + (k - 140)];
    emb[idx] = v;
}

// ---------------------------------------------------------------------------
// Phase 1: input-gate GEMM.
// xg layout: [dir][t][bpair(64)][gj(1024)][2]  (b = bpair*2 + c)
// ---------------------------------------------------------------------------
__global__ void __launch_bounds__(256) gemm_xg(
    const float* __restrict__ emb,
    const float* __restrict__ wihf, const float* __restrict__ bihf, const float* __restrict__ bhhf,
    const float* __restrict__ wihb, const float* __restrict__ bihb, const float* __restrict__ bhhb,
    float* __restrict__ xg)
{
    int gt  = blockIdx.x;
    int t   = blockIdx.y;
    int dir = blockIdx.z;
    const float* w  = dir ? wihb : wihf;
    const float* bi = dir ? bihb : bihf;
    const float* bh = dir ? bhhb : bhhf;
    int gj0 = gt * 128;

    __shared__ float wsh[32][132];   // [k][gj], padded
    __shared__ float esh[32][132];   // [k][b],  padded

    int tid = threadIdx.x;
    int tx = tid & 15, ty = tid >> 4;

    float acc[8][8];
    #pragma unroll
    for (int i = 0; i < 8; ++i)
        #pragma unroll
        for (int j = 0; j < 8; ++j) acc[i][j] = 0.f;

    for (int k0 = 0; k0 < IND_; k0 += 32) {
        __syncthreads();
        #pragma unroll
        for (int m = 0; m < 16; ++m) {
            int e = m * 256 + tid;        // 0..4095
            int k = e & 31, g = e >> 5;   // g: row (gj or b)
            wsh[k][g] = w[(gj0 + g) * IND_ + k0 + k];
            esh[k][g] = emb[(g * L_ + t) * IND_ + k0 + k];
        }
        __syncthreads();
        #pragma unroll
        for (int k = 0; k < 32; ++k) {
            float wv[8], ev[8];
            #pragma unroll
            for (int q = 0; q < 8; ++q) wv[q] = wsh[k][ty * 8 + q];
            #pragma unroll
            for (int q = 0; q < 8; ++q) ev[q] = esh[k][tx * 8 + q];
            #pragma unroll
            for (int i = 0; i < 8; ++i)
                #pragma unroll
                for (int j = 0; j < 8; ++j) acc[i][j] = fmaf(wv[i], ev[j], acc[i][j]);
        }
    }
    #pragma unroll
    for (int i = 0; i < 8; ++i) {
        int gj = gj0 + ty * 8 + i;
        float bias = bi[gj] + bh[gj];
        #pragma unroll
        for (int j = 0; j < 8; ++j) {
            int b = tx * 8 + j;
            xg[((((size_t)dir * L_ + t) * 64 + (b >> 1)) * 1024 + gj) * 2 + (b & 1)]
                = acc[i][j] + bias;
        }
    }
}

// ---------------------------------------------------------------------------
// Phase 1.5: pack recurrent weights to f16x2.
// wp16[dir][p(128)][hid(256)][gate(4)] : uint = {f16(w[g][hid][2p]), f16(w[g][hid][2p+1])}
// ---------------------------------------------------------------------------
__global__ void whh_pack16(const float* __restrict__ whhf, const float* __restrict__ whhb,
                           unsigned* __restrict__ wp)
{
    int gid = blockIdx.x * 256 + threadIdx.x;   // exactly 2*128*256*4 threads
    int g   = gid & 3;
    int h   = (gid >> 2) & 255;
    int p   = (gid >> 10) & 127;
    int dir = gid >> 17;
    const float* whh = dir ? whhb : whhf;
    const float* row = whh + (size_t)(g * 256 + h) * HID_;
    wp[gid] = pack2(row[2 * p], row[2 * p + 1]);
}

// ---------------------------------------------------------------------------
// Phase 2: BiLSTM scan, k-split for wave overlap. 128 blocks x 1024 threads
// (16 waves/CU = 4/SIMD). R4/R6 lesson: at 1 wave/SIMD the VMEM/LDS/VALU
// phases SERIALIZE (measured time = phase sum, 5.4us/step, byte cuts didn't
// help). Thread (h, q=tid>>8) computes k-quarter q (32 of 128 slices) for
// hidden unit h, 4 gates, 2 batch cols; partials reduce via 32KB pbuf.
// q0's slices 0..23 come from a 96KB LDS tier; streamed = 416KB/step/CU.
// With 4 waves/SIMD the phases overlap: step ~ max(VMEM 2.9-4.4, LDS ~1.7,
// VALU ~1.3) instead of sum.
// ---------------------------------------------------------------------------
__global__ void __launch_bounds__(1024, 4) lstm_scan_s(
    const float* __restrict__ xg, const uint4* __restrict__ wp16,
    float* __restrict__ xf2, float* __restrict__ xb2)
{
    int blk = blockIdx.x;
    int dir = blk >> 6;            // 0..1
    int bp  = blk & 63;            // b-pair index
    int tid = threadIdx.x;
    int h   = tid & 255;           // hidden unit
    int q   = tid >> 8;            // k-quarter 0..3 (wave-uniform)

    const uint4* wt = wp16 + (size_t)dir * 128 * 256;   // [p][hid] uint4
    float* xo = dir ? xb2 : xf2;

    __shared__ uint2 hA[128];            // [p] = {bs0 f16x2, bs1 f16x2}
    __shared__ uint2 hB[128];
    __shared__ float pbuf[4][8][256];    // [q][gate*2+bs][h], 32KB, b32 conflict-free
    __shared__ uint4 wlds[SLDS][256];    // q0's p=0..SLDS-1, 96KB

    // stage LDS weight tier (cooperative, coalesced, once)
    for (int m = q; m < SLDS; m += 4)
        wlds[m][h] = wt[m * 256 + h];

    if (tid < 256) ((unsigned*)hA)[tid] = 0u;
    float c0 = 0.f, c1 = 0.f;            // live only in q==0 threads
    __syncthreads();

    int pq0  = q * 32;                   // this thread's k-slice range
    int sbeg = (q == 0) ? SLDS : pq0;    // streamed part of the range
    int send = pq0 + 32;

    for (int t = 0; t < L_; ++t) {
        int slot = dir ? (L_ - 1 - t) : t;
        const uint2* hp = (t & 1) ? hB : hA;
        unsigned*    hw = (unsigned*)((t & 1) ? hA : hB);

        // epilogue threads preload their 4 xg gates (hidden under k-loop)
        float2 gI, gF, gG, gO;
        if (q == 0) {
            const float* xbase = xg + (((size_t)dir * L_ + slot) * 64 + bp) * 2048;
            gI = *(const float2*)(xbase + (0 * 256 + h) * 2);
            gF = *(const float2*)(xbase + (1 * 256 + h) * 2);
            gG = *(const float2*)(xbase + (2 * 256 + h) * 2);
            gO = *(const float2*)(xbase + (3 * 256 + h) * 2);
        }

        float aI0=0.f, aI1=0.f, aF0=0.f, aF1=0.f;
        float aG0=0.f, aG1=0.f, aO0=0.f, aO1=0.f;

        // --- streamed slices of this thread's quarter
        #pragma unroll 8
        for (int p = sbeg; p < send; ++p) {
            uint4 w4 = wt[p * 256 + h];   // coalesced 1KB/wave from L2
            uint2 hb = hp[p];             // broadcast b64
            aI0 = fdot2_(w4.x, hb.x, aI0); aI1 = fdot2_(w4.x, hb.y, aI1);
            aF0 = fdot2_(w4.y, hb.x, aF0); aF1 = fdot2_(w4.y, hb.y, aF1);
            aG0 = fdot2_(w4.z, hb.x, aG0); aG1 = fdot2_(w4.z, hb.y, aG1);
            aO0 = fdot2_(w4.w, hb.x, aO0); aO1 = fdot2_(w4.w, hb.y, aO1);
        }
        // --- LDS-resident slices (q0 only; wave-uniform branch)
        if (q == 0) {
            #pragma unroll 8
            for (int p = 0; p < SLDS; ++p) {
                uint4 w4 = wlds[p][h];
                uint2 hb = hp[p];
                aI0 = fdot2_(w4.x, hb.x, aI0); aI1 = fdot2_(w4.x, hb.y, aI1);
                aF0 = fdot2_(w4.y, hb.x, aF0); aF1 = fdot2_(w4.y, hb.y, aF1);
                aG0 = fdot2_(w4.z, hb.x, aG0); aG1 = fdot2_(w4.z, hb.y, aG1);
                aO0 = fdot2_(w4.w, hb.x, aO0); aO1 = fdot2_(w4.w, hb.y, aO1);
            }
        }

        // publish partials (b32, lanes = consecutive h -> conflict-free)
        pbuf[q][0][h] = aI0; pbuf[q][1][h] = aI1;
        pbuf[q][2][h] = aF0; pbuf[q][3][h] = aF1;
        pbuf[q][4][h] = aG0; pbuf[q][5][h] = aG1;
        pbuf[q][6][h] = aO0; pbuf[q][7][h] = aO1;
        __syncthreads();   // pbuf complete

        if (q == 0) {
            float sI0 = pbuf[0][0][h] + pbuf[1][0][h] + pbuf[2][0][h] + pbuf[3][0][h] + gI.x;
            float sI1 = pbuf[0][1][h] + pbuf[1][1][h] + pbuf[2][1][h] + pbuf[3][1][h] + gI.y;
            float sF0 = pbuf[0][2][h] + pbuf[1][2][h] + pbuf[2][2][h] + pbuf[3][2][h] + gF.x;
            float sF1 = pbuf[0][3][h] + pbuf[1][3][h] + pbuf[2][3][h] + pbuf[3][3][h] + gF.y;
            float sG0 = pbuf[0][4][h] + pbuf[1][4][h] + pbuf[2][4][h] + pbuf[3][4][h] + gG.x;
            float sG1 = pbuf[0][5][h] + pbuf[1][5][h] + pbuf[2][5][h] + pbuf[3][5][h] + gG.y;
            float sO0 = pbuf[0][6][h] + pbuf[1][6][h] + pbuf[2][6][h] + pbuf[3][6][h] + gO.x;
            float sO1 = pbuf[0][7][h] + pbuf[1][7][h] + pbuf[2][7][h] + pbuf[3][7][h] + gO.y;

            float i0 = 1.f / (1.f + expf(-sI0));
            float f0 = 1.f / (1.f + expf(-sF0));
            float g0 = tanhf(sG0);
            float o0 = 1.f / (1.f + expf(-sO0));
            c0 = f0 * c0 + i0 * g0;
            float hv0 = o0 * tanhf(c0);

            float i1 = 1.f / (1.f + expf(-sI1));
            float f1 = 1.f / (1.f + expf(-sF1));
            float g1 = tanhf(sG1);
            float o1 = 1.f / (1.f + expf(-sO1));
            c1 = f1 * c1 + i1 * g1;
            float hv1 = o1 * tanhf(c1);

            // pack h to f16x2 pairs: threads 2p,2p+1 exchange via shfl_xor(1)
            float n0 = __shfl_xor(hv0, 1);
            float n1 = __shfl_xor(hv1, 1);
            hw[h] = (h & 1) ? pack2(n1, hv1)    // odd h -> [p][bs1]
                            : pack2(hv0, n0);   // even h -> [p][bs0]
            float* xp = xo + ((size_t)slot * 64 + bp) * 512 + h * 2;
            xp[0] = hv0; xp[1] = hv1;
        }
        __syncthreads();   // hw + pbuf reuse protected
    }
}

// remap [slot][bp][hid*2+bs] -> x[slot][hid][b], summing directions.
// Writes lane-contiguous; scatter on the read side (L2/L3 absorbs).
__global__ void x_add(const float* __restrict__ xf2, const float* __restrict__ xb2,
                      float* __restrict__ x)
{
    int idx = blockIdx.x * 256 + threadIdx.x;   // exactly L_*HID_*B_ threads
    int b    = idx & 127;
    int j    = (idx >> 7) & 255;
    int slot = idx >> 15;
    int src  = ((slot * 64 + (b >> 1)) * 512) + j * 2 + (b & 1);
    x[idx] = xf2[src] + xb2[src];
}

// ---------------------------------------------------------------------------
// Phase 3: entity features, attention, primary capsules
// ---------------------------------------------------------------------------
__global__ void find_entity(const int* __restrict__ pos1, const int* __restrict__ pos2,
                            int* __restrict__ e)
{
    int b = threadIdx.x;
    int e1 = 0, e2 = 0;
    for (int l = L_ - 1; l >= 0; --l) if (pos1[b * L_ + l] == ENTITY) e1 = l;
    for (int l = L_ - 1; l >= 0; --l) if (pos2[b * L_ + l] == ENTITY) e2 = l;
    e[b] = e1; e[B_ + b] = e2;
}

__global__ void compute_he(const float* __restrict__ x, const int* __restrict__ e,
                           float* __restrict__ he)
{
    int j = blockIdx.x, b = threadIdx.x;
    int e1 = e[b], e2 = e[B_ + b];
    he[j * B_ + b] = x[((size_t)e1 * HID_ + j) * B_ + b] + x[((size_t)e2 * HID_ + j) * B_ + b];
}

__global__ void att_logits(const float* __restrict__ x, const float* __restrict__ he,
                           float* __restrict__ logits)
{
    int l = blockIdx.x, b = threadIdx.x;
    float acc = 0.f;
    for (int j = 0; j < HID_; ++j)
        acc = fmaf(x[((size_t)l * HID_ + j) * B_ + b], he[j * B_ + b], acc);
    logits[l * B_ + b] = acc;
}

__global__ void att_softmax(const float* __restrict__ logits, float* __restrict__ att)
{
    int b = threadIdx.x;
    float m = -1e30f;
    for (int l = 0; l < L_; ++l) m = fmaxf(m, logits[l * B_ + b]);
    float s = 0.f;
    for (int l = 0; l < L_; ++l) s += expf(logits[l * B_ + b] - m);
    float inv = 1.f / s;
    for (int l = 0; l < L_; ++l) att[l * B_ + b] = expf(logits[l * B_ + b] - m) * inv;
}

// primary capsules: u[i][b][c], squashed
__global__ void u_squash(const float* __restrict__ x, float* __restrict__ u)
{
    int i = blockIdx.x, b = threadIdx.x;
    int l = i >> 4, cap = i & 15;
    float vals[16]; float n2 = 0.f;
    #pragma unroll
    for (int c2 = 0; c2 < 16; ++c2) {
        float v = x[((size_t)l * HID_ + cap * 16 + c2) * B_ + b];
        vals[c2] = v; n2 = fmaf(v, v, n2);
    }
    float f = (n2 / (1.f + n2)) / sqrtf(n2 + 1e-9f);
    #pragma unroll
    for (int c2 = 0; c2 < 16; ++c2)
        u[((size_t)i * B_ + b) * 16 + c2] = vals[c2] * f;
}

// ---------------------------------------------------------------------------
// Phase 4: routing
// ---------------------------------------------------------------------------
__global__ void bb_init(const float* __restrict__ br, float* __restrict__ bb)
{
    int idx = blockIdx.x * 256 + threadIdx.x;   // exactly B_*NI*NCLASS threads
    bb[idx] = br[idx % (NI * NCLASS)];
}

__global__ void __launch_bounds__(320) s_pass(
    const float* __restrict__ u, const float* __restrict__ W,
    const float* __restrict__ bb, const float* __restrict__ att,
    float* __restrict__ partial)
{
    int ic = blockIdx.x, bt = blockIdx.y;
    int i0 = ic * 16, b0 = bt * 16;
    __shared__ float C[16][16][20];   // [bl][il][o], padded
    int tid = threadIdx.x;
    if (tid < 256) {
        int bl = tid >> 4, il = tid & 15;
        int b = b0 + bl, i = i0 + il;
        const float* bbp = bb + ((size_t)b * NI + i) * NCLASS;
        float m = bbp[0];
        #pragma unroll
        for (int o = 1; o < NCLASS; ++o) m = fmaxf(m, bbp[o]);
        float s = 0.f; float e[NCLASS];
        #pragma unroll
        for (int o = 0; o < NCLASS; ++o) { e[o] = expf(bbp[o] - m); s += e[o]; }
        float al = att[(i >> 4) * B_ + b] / s;
        #pragma unroll
        for (int o = 0; o < NCLASS; ++o) C[bl][il][o] = e[o] * al;
    }
    __syncthreads();
    if (tid >= OD) return;
    int od = tid, o = od >> 4;
    float acc[16];
    #pragma unroll
    for (int bl = 0; bl < 16; ++bl) acc[bl] = 0.f;
    for (int il = 0; il < 16; ++il) {
        int i = i0 + il;
        const float* wp = W + (size_t)i * 16 * OD + od;
        float w[16];
        #pragma unroll
        for (int c2 = 0; c2 < 16; ++c2) w[c2] = wp[c2 * OD];     // coalesced over od
        const float* up = u + ((size_t)i * B_ + b0) * 16;        // uniform -> s_load
        #pragma unroll
        for (int bl = 0; bl < 16; ++bl) {
            float uh = 0.f;
            #pragma unroll
            for (int c2 = 0; c2 < 16; ++c2) uh = fmaf(up[bl * 16 + c2], w[c2], uh);
            acc[bl] = fmaf(C[bl][il][o], uh, acc[bl]);
        }
    }
    #pragma unroll
    for (int bl = 0; bl < 16; ++bl)
        partial[((size_t)ic * B_ + b0 + bl) * OD + od] = acc[bl];
}

__global__ void s_reduce(const float* __restrict__ partial, float* __restrict__ s)
{
    int idx = blockIdx.x * 256 + threadIdx.x;   // exactly B_*OD threads
    int b = idx / OD, od = idx - b * OD;
    float acc = 0.f;
    for (int ic = 0; ic < 100; ++ic) acc += partial[((size_t)ic * B_ + b) * OD + od];
    s[idx] = acc;
}

__global__ void squash_v(const float* __restrict__ s, float* __restrict__ v,
                         float* __restrict__ out, int write_out)
{
    int idx = blockIdx.x * 256 + threadIdx.x;
    if (idx >= B_ * NCLASS) return;
    const float* sp = s + (size_t)idx * 16;     // b*304 + o*16 == idx*16
    float vals[16]; float n2 = 0.f;
    #pragma unroll
    for (int d = 0; d < 16; ++d) { vals[d] = sp[d]; n2 = fmaf(vals[d], vals[d], n2); }
    float f = (n2 / (1.f + n2)) / sqrtf(n2 + 1e-9f);
    float n2v = 0.f;
    #pragma unroll
    for (int d = 0; d < 16; ++d) {
        float vv = vals[d] * f;
        v[(size_t)idx * 16 + d] = vv;
        n2v = fmaf(vv, vv, n2v);
    }
    if (write_out) out[idx] = sqrtf(n2v + 1e-9f);
}

__global__ void __launch_bounds__(320) bb_pass(
    const float* __restrict__ u, const float* __restrict__ W,
    const float* __restrict__ v, float* __restrict__ bb)
{
    int ic = blockIdx.x, bt = blockIdx.y;
    int i0 = ic * 16, b0 = bt * 16;
    int tid = threadIdx.x;
    if (tid >= OD) return;
    int od = tid, o = od >> 4, d = od & 15;
    float vv[16];
    #pragma unroll
    for (int bl = 0; bl < 16; ++bl) vv[bl] = v[(size_t)(b0 + bl) * OD + od];
    for (int il = 0; il < 16; ++il) {
        int i = i0 + il;
        const float* wp = W + (size_t)i * 16 * OD + od;
        float w[16];
        #pragma unroll
        for (int c2 = 0; c2 < 16; ++c2) w[c2] = wp[c2 * OD];
        const float* up = u + ((size_t)i * B_ + b0) * 16;
        #pragma unroll
        for (int bl = 0; bl < 16; ++bl) {
            float uh = 0.f;
            #pragma unroll
            for (int c2 = 0; c2 < 16; ++c2) uh = fmaf(up[bl * 16 + c2], w[c2], uh);
            float p = uh * vv[bl];
            p += __shfl_xor(p, 1);
            p += __shfl_xor(p, 2);
            p += __shfl_xor(p, 4);
            p += __shfl_xor(p, 8);
            if (d == 0) bb[((size_t)(b0 + bl) * NI + i) * NCLASS + o] += p;
        }
    }
}

// ---------------------------------------------------------------------------
extern "C" void kernel_launch(void* const* d_in, const int* in_sizes, int n_in,
                              void* d_out, int out_size, void* d_ws, size_t ws_size,
                              hipStream_t stream)
{
    (void)in_sizes; (void)n_in; (void)out_size; (void)ws_size;
    const int*   word = (const int*)d_in[0];
    const int*   tag  = (const int*)d_in[1];
    const int*   pos1 = (const int*)d_in[2];
    const int*   pos2 = (const int*)d_in[3];
    const float* we   = (const float*)d_in[4];
    const float* te   = (const float*)d_in[5];
    const float* p1e  = (const float*)d_in[6];
    const float* p2e  = (const float*)d_in[7];
    const float* wihf = (const float*)d_in[8];
    const float* whhf = (const float*)d_in[9];
    const float* bihf = (const float*)d_in[10];
    const float* bhhf = (const float*)d_in[11];
    const float* wihb = (const float*)d_in[12];
    const float* whhb = (const float*)d_in[13];
    const float* bihb = (const float*)d_in[14];
    const float* bhhb = (const float*)d_in[15];
    const float* Wc   = (const float*)d_in[16];
    const float* br   = (const float*)d_in[17];

    float* wsp    = (float*)d_ws;
    float* emb    = wsp;                       //  2,048,000
    float* xg     = wsp + 2048000;             // 26,214,400
    float* xf     = xg + 26214400;             //  3,276,800
    float* xb     = xf + 3276800;              //  3,276,800
    float* he     = xb + 3276800;              //     32,768
    float* logits = he + 32768;                //     12,800
    float* att    = logits + 12800;            //     12,800
    int*   e      = (int*)(att + 12800);       //        256 ints
    // packed f16 recurrent weights alias the (dead-after-gemm_xg) emb region
    unsigned* wp16 = (unsigned*)emb;           //  262,144 uints (1 MB)
    // post-scan buffers alias the (dead-after-scan) xg region
    float* x    = xg;                          //  3,276,800
    float* u    = xg + 3276800;                //  3,276,800
    float* bb   = xg + 6553600;                //  3,891,200
    float* part = xg + 10444800;               //  3,891,200
    float* s    = xg + 14336000;               //     38,912
    float* v    = s + 38912;                   //     38,912
    float* out  = (float*)d_out;

    emb_gather<<<8000, 256, 0, stream>>>(word, tag, pos1, pos2, we, te, p1e, p2e, emb);
    gemm_xg<<<dim3(8, 100, 2), 256, 0, stream>>>(emb, wihf, bihf, bhhf, wihb, bihb, bhhb, xg);
    whh_pack16<<<1024, 256, 0, stream>>>(whhf, whhb, wp16);
    lstm_scan_s<<<128, 1024, 0, stream>>>(xg, (const uint4*)wp16, xf, xb);
    x_add<<<12800, 256, 0, stream>>>(xf, xb, x);
    find_entity<<<1, 128, 0, stream>>>(pos1, pos2, e);
    compute_he<<<256, 128, 0, stream>>>(x, e, he);
    att_logits<<<100, 128, 0, stream>>>(x, he, logits);
    att_softmax<<<1, 128, 0, stream>>>(logits, att);
    u_squash<<<1600, 128, 0, stream>>>(x, u);
    bb_init<<<15200, 256, 0, stream>>>(br, bb);
    for (int it = 0; it < 3; ++it) {
        s_pass<<<dim3(100, 8), 320, 0, stream>>>(u, Wc, bb, att, part);
        s_reduce<<<152, 256, 0, stream>>>(part, s);
        squash_v<<<10, 256, 0, stream>>>(s, v, out, (it == 2) ? 1 : 0);
        if (it < 2) bb_pass<<<dim3(100, 8), 320, 0, stream>>>(u, Wc, v, bb);
    }
}

// Round 8
// 1174.156 us; speedup vs baseline: 17.4530x; 1.2235x over previous
//
#include <hip/hip_runtime.h>
#include <math.h>

#define B_     128
#define L_     100
#define HID_   256
#define IND_   160
#define NCLASS 19
#define CAPD   16
#define NI     1600      // L_ * NUM_CAPS
#define OD     304       // NCLASS * CAPD
#define ENTITY 68

#define SLDS   24        // LDS-resident weight slices (q0's p=0..23), 96KB

typedef _Float16 half2_t __attribute__((ext_vector_type(2)));

__device__ inline half2_t as_h2(unsigned u) {
    union { unsigned u; half2_t h; } x; x.u = u; return x.h;
}
__device__ inline unsigned pack2(float a, float b) {
    union { unsigned u; half2_t h; } x;
    x.h = (half2_t){ (_Float16)a, (_Float16)b };   // RTN converts
    return x.u;
}
__device__ inline float fdot2_(unsigned w, unsigned h, float acc) {
#if __has_builtin(__builtin_amdgcn_fdot2)
    return __builtin_amdgcn_fdot2(as_h2(w), as_h2(h), acc, false);
#else
    half2_t wh = as_h2(w), hh = as_h2(h);
    acc = fmaf((float)wh.x, (float)hh.x, acc);
    return fmaf((float)wh.y, (float)hh.y, acc);
#endif
}

// ---------------------------------------------------------------------------
// Phase 0: embedding gather -> emb [b*L_+t][160]
// ---------------------------------------------------------------------------
__global__ void emb_gather(const int* __restrict__ word, const int* __restrict__ tag,
                           const int* __restrict__ pos1, const int* __restrict__ pos2,
                           const float* __restrict__ we, const float* __restrict__ te,
                           const float* __restrict__ p1e, const float* __restrict__ p2e,
                           float* __restrict__ emb)
{
    int idx = blockIdx.x * 256 + threadIdx.x;          // exactly B_*L_*IND_ threads
    int bt = idx / IND_;
    int k  = idx - bt * IND_;
    float v;
    if (k < 100)      v = we[word[bt] * 100 + k];
    else if (k < 120) v = te[tag[bt] * 20 + (k - 100)];
    else if (k < 140) v = p1e[pos1[bt] * 20 + (k - 120)];
    else              v = p2e[pos2[bt] * 20 + (k - 140)];
    emb[idx] = v;
}

// ---------------------------------------------------------------------------
// Phase 1: input-gate GEMM.
// xg layout: [dir][t][bpair(64)][gj(1024)][2]  (b = bpair*2 + c)
// ---------------------------------------------------------------------------
__global__ void __launch_bounds__(256) gemm_xg(
    const float* __restrict__ emb,
    const float* __restrict__ wihf, const float* __restrict__ bihf, const float* __restrict__ bhhf,
    const float* __restrict__ wihb, const float* __restrict__ bihb, const float* __restrict__ bhhb,
    float* __restrict__ xg)
{
    int gt  = blockIdx.x;
    int t   = blockIdx.y;
    int dir = blockIdx.z;
    const float* w  = dir ? wihb : wihf;
    const float* bi = dir ? bihb : bihf;
    const float* bh = dir ? bhhb : bhhf;
    int gj0 = gt * 128;

    __shared__ float wsh[32][132];   // [k][gj], padded
    __shared__ float esh[32][132];   // [k][b],  padded

    int tid = threadIdx.x;
    int tx = tid & 15, ty = tid >> 4;

    float acc[8][8];
    #pragma unroll
    for (int i = 0; i < 8; ++i)
        #pragma unroll
        for (int j = 0; j < 8; ++j) acc[i][j] = 0.f;

    for (int k0 = 0; k0 < IND_; k0 += 32) {
        __syncthreads();
        #pragma unroll
        for (int m = 0; m < 16; ++m) {
            int e = m * 256 + tid;        // 0..4095
            int k = e & 31, g = e >> 5;   // g: row (gj or b)
            wsh[k][g] = w[(gj0 + g) * IND_ + k0 + k];
            esh[k][g] = emb[(g * L_ + t) * IND_ + k0 + k];
        }
        __syncthreads();
        #pragma unroll
        for (int k = 0; k < 32; ++k) {
            float wv[8], ev[8];
            #pragma unroll
            for (int q = 0; q < 8; ++q) wv[q] = wsh[k][ty * 8 + q];
            #pragma unroll
            for (int q = 0; q < 8; ++q) ev[q] = esh[k][tx * 8 + q];
            #pragma unroll
            for (int i = 0; i < 8; ++i)
                #pragma unroll
                for (int j = 0; j < 8; ++j) acc[i][j] = fmaf(wv[i], ev[j], acc[i][j]);
        }
    }
    #pragma unroll
    for (int i = 0; i < 8; ++i) {
        int gj = gj0 + ty * 8 + i;
        float bias = bi[gj] + bh[gj];
        #pragma unroll
        for (int j = 0; j < 8; ++j) {
            int b = tx * 8 + j;
            xg[((((size_t)dir * L_ + t) * 64 + (b >> 1)) * 1024 + gj) * 2 + (b & 1)]
                = acc[i][j] + bias;
        }
    }
}

// ---------------------------------------------------------------------------
// Phase 1.5: pack recurrent weights to f16x2.
// wp16[dir][p(128)][hid(256)][gate(4)] : uint = {f16(w[g][hid][2p]), f16(w[g][hid][2p+1])}
// ---------------------------------------------------------------------------
__global__ void whh_pack16(const float* __restrict__ whhf, const float* __restrict__ whhb,
                           unsigned* __restrict__ wp)
{
    int gid = blockIdx.x * 256 + threadIdx.x;   // exactly 2*128*256*4 threads
    int g   = gid & 3;
    int h   = (gid >> 2) & 255;
    int p   = (gid >> 10) & 127;
    int dir = gid >> 17;
    const float* whh = dir ? whhb : whhf;
    const float* row = whh + (size_t)(g * 256 + h) * HID_;
    wp[gid] = pack2(row[2 * p], row[2 * p + 1]);
}

// ---------------------------------------------------------------------------
// Phase 2: BiLSTM scan, k-split for wave overlap (R7 verified: 478us,
// within ~10% of the per-CU VMEM floor). Unchanged this round.
// ---------------------------------------------------------------------------
__global__ void __launch_bounds__(1024, 4) lstm_scan_s(
    const float* __restrict__ xg, const uint4* __restrict__ wp16,
    float* __restrict__ xf2, float* __restrict__ xb2)
{
    int blk = blockIdx.x;
    int dir = blk >> 6;            // 0..1
    int bp  = blk & 63;            // b-pair index
    int tid = threadIdx.x;
    int h   = tid & 255;           // hidden unit
    int q   = tid >> 8;            // k-quarter 0..3 (wave-uniform)

    const uint4* wt = wp16 + (size_t)dir * 128 * 256;   // [p][hid] uint4
    float* xo = dir ? xb2 : xf2;

    __shared__ uint2 hA[128];            // [p] = {bs0 f16x2, bs1 f16x2}
    __shared__ uint2 hB[128];
    __shared__ float pbuf[4][8][256];    // [q][gate*2+bs][h], 32KB, b32 conflict-free
    __shared__ uint4 wlds[SLDS][256];    // q0's p=0..SLDS-1, 96KB

    // stage LDS weight tier (cooperative, coalesced, once)
    for (int m = q; m < SLDS; m += 4)
        wlds[m][h] = wt[m * 256 + h];

    if (tid < 256) ((unsigned*)hA)[tid] = 0u;
    float c0 = 0.f, c1 = 0.f;            // live only in q==0 threads
    __syncthreads();

    int pq0  = q * 32;                   // this thread's k-slice range
    int sbeg = (q == 0) ? SLDS : pq0;    // streamed part of the range
    int send = pq0 + 32;

    for (int t = 0; t < L_; ++t) {
        int slot = dir ? (L_ - 1 - t) : t;
        const uint2* hp = (t & 1) ? hB : hA;
        unsigned*    hw = (unsigned*)((t & 1) ? hA : hB);

        // epilogue threads preload their 4 xg gates (hidden under k-loop)
        float2 gI, gF, gG, gO;
        if (q == 0) {
            const float* xbase = xg + (((size_t)dir * L_ + slot) * 64 + bp) * 2048;
            gI = *(const float2*)(xbase + (0 * 256 + h) * 2);
            gF = *(const float2*)(xbase + (1 * 256 + h) * 2);
            gG = *(const float2*)(xbase + (2 * 256 + h) * 2);
            gO = *(const float2*)(xbase + (3 * 256 + h) * 2);
        }

        float aI0=0.f, aI1=0.f, aF0=0.f, aF1=0.f;
        float aG0=0.f, aG1=0.f, aO0=0.f, aO1=0.f;

        // --- streamed slices of this thread's quarter
        #pragma unroll 8
        for (int p = sbeg; p < send; ++p) {
            uint4 w4 = wt[p * 256 + h];   // coalesced 1KB/wave from L2
            uint2 hb = hp[p];             // broadcast b64
            aI0 = fdot2_(w4.x, hb.x, aI0); aI1 = fdot2_(w4.x, hb.y, aI1);
            aF0 = fdot2_(w4.y, hb.x, aF0); aF1 = fdot2_(w4.y, hb.y, aF1);
            aG0 = fdot2_(w4.z, hb.x, aG0); aG1 = fdot2_(w4.z, hb.y, aG1);
            aO0 = fdot2_(w4.w, hb.x, aO0); aO1 = fdot2_(w4.w, hb.y, aO1);
        }
        // --- LDS-resident slices (q0 only; wave-uniform branch)
        if (q == 0) {
            #pragma unroll 8
            for (int p = 0; p < SLDS; ++p) {
                uint4 w4 = wlds[p][h];
                uint2 hb = hp[p];
                aI0 = fdot2_(w4.x, hb.x, aI0); aI1 = fdot2_(w4.x, hb.y, aI1);
                aF0 = fdot2_(w4.y, hb.x, aF0); aF1 = fdot2_(w4.y, hb.y, aF1);
                aG0 = fdot2_(w4.z, hb.x, aG0); aG1 = fdot2_(w4.z, hb.y, aG1);
                aO0 = fdot2_(w4.w, hb.x, aO0); aO1 = fdot2_(w4.w, hb.y, aO1);
            }
        }

        // publish partials (b32, lanes = consecutive h -> conflict-free)
        pbuf[q][0][h] = aI0; pbuf[q][1][h] = aI1;
        pbuf[q][2][h] = aF0; pbuf[q][3][h] = aF1;
        pbuf[q][4][h] = aG0; pbuf[q][5][h] = aG1;
        pbuf[q][6][h] = aO0; pbuf[q][7][h] = aO1;
        __syncthreads();   // pbuf complete

        if (q == 0) {
            float sI0 = pbuf[0][0][h] + pbuf[1][0][h] + pbuf[2][0][h] + pbuf[3][0][h] + gI.x;
            float sI1 = pbuf[0][1][h] + pbuf[1][1][h] + pbuf[2][1][h] + pbuf[3][1][h] + gI.y;
            float sF0 = pbuf[0][2][h] + pbuf[1][2][h] + pbuf[2][2][h] + pbuf[3][2][h] + gF.x;
            float sF1 = pbuf[0][3][h] + pbuf[1][3][h] + pbuf[2][3][h] + pbuf[3][3][h] + gF.y;
            float sG0 = pbuf[0][4][h] + pbuf[1][4][h] + pbuf[2][4][h] + pbuf[3][4][h] + gG.x;
            float sG1 = pbuf[0][5][h] + pbuf[1][5][h] + pbuf[2][5][h] + pbuf[3][5][h] + gG.y;
            float sO0 = pbuf[0][6][h] + pbuf[1][6][h] + pbuf[2][6][h] + pbuf[3][6][h] + gO.x;
            float sO1 = pbuf[0][7][h] + pbuf[1][7][h] + pbuf[2][7][h] + pbuf[3][7][h] + gO.y;

            float i0 = 1.f / (1.f + expf(-sI0));
            float f0 = 1.f / (1.f + expf(-sF0));
            float g0 = tanhf(sG0);
            float o0 = 1.f / (1.f + expf(-sO0));
            c0 = f0 * c0 + i0 * g0;
            float hv0 = o0 * tanhf(c0);

            float i1 = 1.f / (1.f + expf(-sI1));
            float f1 = 1.f / (1.f + expf(-sF1));
            float g1 = tanhf(sG1);
            float o1 = 1.f / (1.f + expf(-sO1));
            c1 = f1 * c1 + i1 * g1;
            float hv1 = o1 * tanhf(c1);

            // pack h to f16x2 pairs: threads 2p,2p+1 exchange via shfl_xor(1)
            float n0 = __shfl_xor(hv0, 1);
            float n1 = __shfl_xor(hv1, 1);
            hw[h] = (h & 1) ? pack2(n1, hv1)    // odd h -> [p][bs1]
                            : pack2(hv0, n0);   // even h -> [p][bs0]
            float* xp = xo + ((size_t)slot * 64 + bp) * 512 + h * 2;
            xp[0] = hv0; xp[1] = hv1;
        }
        __syncthreads();   // hw + pbuf reuse protected
    }
}

// remap [slot][bp][hid*2+bs] -> x[slot][hid][b], summing directions.
__global__ void x_add(const float* __restrict__ xf2, const float* __restrict__ xb2,
                      float* __restrict__ x)
{
    int idx = blockIdx.x * 256 + threadIdx.x;   // exactly L_*HID_*B_ threads
    int b    = idx & 127;
    int j    = (idx >> 7) & 255;
    int slot = idx >> 15;
    int src  = ((slot * 64 + (b >> 1)) * 512) + j * 2 + (b & 1);
    x[idx] = xf2[src] + xb2[src];
}

// ---------------------------------------------------------------------------
// Phase 2.5: pack W_caps to f16 c-pairs (runs after x_add; lives in dead xf/xb).
// Wc16[i][cp(8)][od(304)] : uint = {f16(W[i][2cp][od]), f16(W[i][2cp+1][od])}
// Halves the 31MB-per-pass W stream and enables dot2 in routing.
// ---------------------------------------------------------------------------
__global__ void wc_pack16(const float* __restrict__ W, unsigned* __restrict__ wc)
{
    int gid = blockIdx.x * 256 + threadIdx.x;   // exactly 1600*8*304 threads
    int od  = gid % OD;
    int rest = gid / OD;
    int cp  = rest & 7;
    int i   = rest >> 3;
    float a = W[((size_t)i * 16 + 2 * cp) * OD + od];       // coalesced over od
    float b = W[((size_t)i * 16 + 2 * cp + 1) * OD + od];
    wc[gid] = pack2(a, b);                                  // gid == (i*8+cp)*OD+od
}

// ---------------------------------------------------------------------------
// Phase 3: entity features, attention, primary capsules
// ---------------------------------------------------------------------------
__global__ void find_entity(const int* __restrict__ pos1, const int* __restrict__ pos2,
                            int* __restrict__ e)
{
    int b = threadIdx.x;
    int e1 = 0, e2 = 0;
    for (int l = L_ - 1; l >= 0; --l) if (pos1[b * L_ + l] == ENTITY) e1 = l;
    for (int l = L_ - 1; l >= 0; --l) if (pos2[b * L_ + l] == ENTITY) e2 = l;
    e[b] = e1; e[B_ + b] = e2;
}

__global__ void compute_he(const float* __restrict__ x, const int* __restrict__ e,
                           float* __restrict__ he)
{
    int j = blockIdx.x, b = threadIdx.x;
    int e1 = e[b], e2 = e[B_ + b];
    he[j * B_ + b] = x[((size_t)e1 * HID_ + j) * B_ + b] + x[((size_t)e2 * HID_ + j) * B_ + b];
}

__global__ void att_logits(const float* __restrict__ x, const float* __restrict__ he,
                           float* __restrict__ logits)
{
    int l = blockIdx.x, b = threadIdx.x;
    float acc = 0.f;
    for (int j = 0; j < HID_; ++j)
        acc = fmaf(x[((size_t)l * HID_ + j) * B_ + b], he[j * B_ + b], acc);
    logits[l * B_ + b] = acc;
}

__global__ void att_softmax(const float* __restrict__ logits, float* __restrict__ att)
{
    int b = threadIdx.x;
    float m = -1e30f;
    for (int l = 0; l < L_; ++l) m = fmaxf(m, logits[l * B_ + b]);
    float s = 0.f;
    for (int l = 0; l < L_; ++l) s += expf(logits[l * B_ + b] - m);
    float inv = 1.f / s;
    for (int l = 0; l < L_; ++l) att[l * B_ + b] = expf(logits[l * B_ + b] - m) * inv;
}

// primary capsules squashed + packed to f16 c-pairs: u16[i][b][cp(8)]
// (u is only ever consumed via the uh dot products -> fp16 is safe here)
__global__ void u_squash16(const float* __restrict__ x, unsigned* __restrict__ u16)
{
    int i = blockIdx.x, b = threadIdx.x;
    int l = i >> 4, cap = i & 15;
    float vals[16]; float n2 = 0.f;
    #pragma unroll
    for (int c2 = 0; c2 < 16; ++c2) {
        float v = x[((size_t)l * HID_ + cap * 16 + c2) * B_ + b];
        vals[c2] = v; n2 = fmaf(v, v, n2);
    }
    float f = (n2 / (1.f + n2)) / sqrtf(n2 + 1e-9f);
    #pragma unroll
    for (int cp = 0; cp < 8; ++cp)
        u16[((size_t)i * B_ + b) * 8 + cp] = pack2(vals[2 * cp] * f, vals[2 * cp + 1] * f);
}

// ---------------------------------------------------------------------------
// Phase 4: routing (u_hat contraction in fp16 dot2: 16 FMA -> 8 v_dot2)
// ---------------------------------------------------------------------------
__global__ void bb_init(const float* __restrict__ br, float* __restrict__ bb)
{
    int idx = blockIdx.x * 256 + threadIdx.x;   // exactly B_*NI*NCLASS threads
    bb[idx] = br[idx % (NI * NCLASS)];
}

__global__ void __launch_bounds__(320) s_pass16(
    const unsigned* __restrict__ u16, const unsigned* __restrict__ Wc16,
    const float* __restrict__ bb, const float* __restrict__ att,
    float* __restrict__ partial)
{
    int ic = blockIdx.x, bt = blockIdx.y;
    int i0 = ic * 16, b0 = bt * 16;
    __shared__ float C[16][16][20];   // [bl][il][o], padded
    int tid = threadIdx.x;
    if (tid < 256) {
        int bl = tid >> 4, il = tid & 15;
        int b = b0 + bl, i = i0 + il;
        const float* bbp = bb + ((size_t)b * NI + i) * NCLASS;
        float m = bbp[0];
        #pragma unroll
        for (int o = 1; o < NCLASS; ++o) m = fmaxf(m, bbp[o]);
        float s = 0.f; float e[NCLASS];
        #pragma unroll
        for (int o = 0; o < NCLASS; ++o) { e[o] = expf(bbp[o] - m); s += e[o]; }
        float al = att[(i >> 4) * B_ + b] / s;
        #pragma unroll
        for (int o = 0; o < NCLASS; ++o) C[bl][il][o] = e[o] * al;
    }
    __syncthreads();
    if (tid >= OD) return;
    int od = tid, o = od >> 4;
    float acc[16];
    #pragma unroll
    for (int bl = 0; bl < 16; ++bl) acc[bl] = 0.f;
    for (int il = 0; il < 16; ++il) {
        int i = i0 + il;
        const unsigned* wp = Wc16 + (size_t)i * 8 * OD + od;
        unsigned w2[8];
        #pragma unroll
        for (int cp = 0; cp < 8; ++cp) w2[cp] = wp[cp * OD];     // coalesced over od
        const unsigned* up = u16 + ((size_t)i * B_ + b0) * 8;    // uniform -> s_load
        #pragma unroll
        for (int bl = 0; bl < 16; ++bl) {
            float uh = 0.f;
            #pragma unroll
            for (int cp = 0; cp < 8; ++cp) uh = fdot2_(up[bl * 8 + cp], w2[cp], uh);
            acc[bl] = fmaf(C[bl][il][o], uh, acc[bl]);
        }
    }
    #pragma unroll
    for (int bl = 0; bl < 16; ++bl)
        partial[((size_t)ic * B_ + b0 + bl) * OD + od] = acc[bl];
}

__global__ void s_reduce(const float* __restrict__ partial, float* __restrict__ s)
{
    int idx = blockIdx.x * 256 + threadIdx.x;   // exactly B_*OD threads
    int b = idx / OD, od = idx - b * OD;
    float acc = 0.f;
    for (int ic = 0; ic < 100; ++ic) acc += partial[((size_t)ic * B_ + b) * OD + od];
    s[idx] = acc;
}

__global__ void squash_v(const float* __restrict__ s, float* __restrict__ v,
                         float* __restrict__ out, int write_out)
{
    int idx = blockIdx.x * 256 + threadIdx.x;
    if (idx >= B_ * NCLASS) return;
    const float* sp = s + (size_t)idx * 16;     // b*304 + o*16 == idx*16
    float vals[16]; float n2 = 0.f;
    #pragma unroll
    for (int d = 0; d < 16; ++d) { vals[d] = sp[d]; n2 = fmaf(vals[d], vals[d], n2); }
    float f = (n2 / (1.f + n2)) / sqrtf(n2 + 1e-9f);
    float n2v = 0.f;
    #pragma unroll
    for (int d = 0; d < 16; ++d) {
        float vv = vals[d] * f;
        v[(size_t)idx * 16 + d] = vv;
        n2v = fmaf(vv, vv, n2v);
    }
    if (write_out) out[idx] = sqrtf(n2v + 1e-9f);
}

__global__ void __launch_bounds__(320) bb_pass16(
    const unsigned* __restrict__ u16, const unsigned* __restrict__ Wc16,
    const float* __restrict__ v, float* __restrict__ bb)
{
    int ic = blockIdx.x, bt = blockIdx.y;
    int i0 = ic * 16, b0 = bt * 16;
    int tid = threadIdx.x;
    if (tid >= OD) return;
    int od = tid, o = od >> 4, d = od & 15;
    float vv[16];
    #pragma unroll
    for (int bl = 0; bl < 16; ++bl) vv[bl] = v[(size_t)(b0 + bl) * OD + od];
    for (int il = 0; il < 16; ++il) {
        int i = i0 + il;
        const unsigned* wp = Wc16 + (size_t)i * 8 * OD + od;
        unsigned w2[8];
        #pragma unroll
        for (int cp = 0; cp < 8; ++cp) w2[cp] = wp[cp * OD];
        const unsigned* up = u16 + ((size_t)i * B_ + b0) * 8;
        #pragma unroll
        for (int bl = 0; bl < 16; ++bl) {
            float uh = 0.f;
            #pragma unroll
            for (int cp = 0; cp < 8; ++cp) uh = fdot2_(up[bl * 8 + cp], w2[cp], uh);
            float p = uh * vv[bl];
            p += __shfl_xor(p, 1);
            p += __shfl_xor(p, 2);
            p += __shfl_xor(p, 4);
            p += __shfl_xor(p, 8);
            if (d == 0) bb[((size_t)(b0 + bl) * NI + i) * NCLASS + o] += p;
        }
    }
}

// ---------------------------------------------------------------------------
extern "C" void kernel_launch(void* const* d_in, const int* in_sizes, int n_in,
                              void* d_out, int out_size, void* d_ws, size_t ws_size,
                              hipStream_t stream)
{
    (void)in_sizes; (void)n_in; (void)out_size; (void)ws_size;
    const int*   word = (const int*)d_in[0];
    const int*   tag  = (const int*)d_in[1];
    const int*   pos1 = (const int*)d_in[2];
    const int*   pos2 = (const int*)d_in[3];
    const float* we   = (const float*)d_in[4];
    const float* te   = (const float*)d_in[5];
    const float* p1e  = (const float*)d_in[6];
    const float* p2e  = (const float*)d_in[7];
    const float* wihf = (const float*)d_in[8];
    const float* whhf = (const float*)d_in[9];
    const float* bihf = (const float*)d_in[10];
    const float* bhhf = (const float*)d_in[11];
    const float* wihb = (const float*)d_in[12];
    const float* whhb = (const float*)d_in[13];
    const float* bihb = (const float*)d_in[14];
    const float* bhhb = (const float*)d_in[15];
    const float* Wc   = (const float*)d_in[16];
    const float* br   = (const float*)d_in[17];

    float* wsp    = (float*)d_ws;
    float* emb    = wsp;                       //  2,048,000
    float* xg     = wsp + 2048000;             // 26,214,400
    float* xf     = xg + 26214400;             //  3,276,800
    float* xb     = xf + 3276800;              //  3,276,800
    float* he     = xb + 3276800;              //     32,768
    float* logits = he + 32768;                //     12,800
    float* att    = logits + 12800;            //     12,800
    int*   e      = (int*)(att + 12800);       //        256 ints
    // packed f16 recurrent weights alias the (dead-after-gemm_xg) emb region
    unsigned* wp16 = (unsigned*)emb;           //  262,144 uints (1 MB)
    // packed f16 W_caps aliases the (dead-after-x_add) xf/xb region
    unsigned* Wc16 = (unsigned*)xf;            //  3,891,200 uints (15.6 MB)
    // post-scan buffers alias the (dead-after-scan) xg region
    float*    x    = xg;                       //  3,276,800
    unsigned* u16  = (unsigned*)(xg + 3276800);//  1,638,400 uints
    float*    bb   = xg + 6553600;             //  3,891,200
    float*    part = xg + 10444800;            //  3,891,200
    float*    s    = xg + 14336000;            //     38,912
    float*    v    = s + 38912;                //     38,912
    float*    out  = (float*)d_out;

    emb_gather<<<8000, 256, 0, stream>>>(word, tag, pos1, pos2, we, te, p1e, p2e, emb);
    gemm_xg<<<dim3(8, 100, 2), 256, 0, stream>>>(emb, wihf, bihf, bhhf, wihb, bihb, bhhb, xg);
    whh_pack16<<<1024, 256, 0, stream>>>(whhf, whhb, wp16);
    lstm_scan_s<<<128, 1024, 0, stream>>>(xg, (const uint4*)wp16, xf, xb);
    x_add<<<12800, 256, 0, stream>>>(xf, xb, x);
    wc_pack16<<<15200, 256, 0, stream>>>(Wc, Wc16);   // after x_add: xf/xb dead
    find_entity<<<1, 128, 0, stream>>>(pos1, pos2, e);
    compute_he<<<256, 128, 0, stream>>>(x, e, he);
    att_logits<<<100, 128, 0, stream>>>(x, he, logits);
    att_softmax<<<1, 128, 0, stream>>>(logits, att);
    u_squash16<<<1600, 128, 0, stream>>>(x, u16);
    bb_init<<<15200, 256, 0, stream>>>(br, bb);
    for (int it = 0; it < 3; ++it) {
        s_pass16<<<dim3(100, 8), 320, 0, stream>>>(u16, Wc16, bb, att, part);
        s_reduce<<<152, 256, 0, stream>>>(part, s);
        squash_v<<<10, 256, 0, stream>>>(s, v, out, (it == 2) ? 1 : 0);
        if (it < 2) bb_pass16<<<dim3(100, 8), 320, 0, stream>>>(u16, Wc16, v, bb);
    }
}

// Round 9
// 1088.598 us; speedup vs baseline: 18.8248x; 1.0786x over previous
//
#include <hip/hip_runtime.h>
#include <math.h>

#define B_     128
#define L_     100
#define HID_   256
#define IND_   160
#define NCLASS 19
#define CAPD   16
#define NI     1600      // L_ * NUM_CAPS
#define OD     304       // NCLASS * CAPD
#define ENTITY 68

#define SLDS   24        // LDS-resident weight slices (q0's p=0..23), 96KB

typedef _Float16 half2_t __attribute__((ext_vector_type(2)));

__device__ inline half2_t as_h2(unsigned u) {
    union { unsigned u; half2_t h; } x; x.u = u; return x.h;
}
__device__ inline unsigned pack2(float a, float b) {
    union { unsigned u; half2_t h; } x;
    x.h = (half2_t){ (_Float16)a, (_Float16)b };   // RTN converts
    return x.u;
}
__device__ inline float fdot2_(unsigned w, unsigned h, float acc) {
#if __has_builtin(__builtin_amdgcn_fdot2)
    return __builtin_amdgcn_fdot2(as_h2(w), as_h2(h), acc, false);
#else
    half2_t wh = as_h2(w), hh = as_h2(h);
    acc = fmaf((float)wh.x, (float)hh.x, acc);
    return fmaf((float)wh.y, (float)hh.y, acc);
#endif
}

// ---------------------------------------------------------------------------
// Phase 0: embedding gather -> f16-pair emb16 [b*L_+t][kp(80)]
// Segment boundaries (100/120/140) are even, so a k-pair never crosses one.
// ---------------------------------------------------------------------------
__global__ void emb_gather16(const int* __restrict__ word, const int* __restrict__ tag,
                             const int* __restrict__ pos1, const int* __restrict__ pos2,
                             const float* __restrict__ we, const float* __restrict__ te,
                             const float* __restrict__ p1e, const float* __restrict__ p2e,
                             unsigned* __restrict__ emb16)
{
    int idx = blockIdx.x * 256 + threadIdx.x;          // exactly B_*L_*80 threads
    int bt = idx / 80;
    int kp = idx - bt * 80;
    int k  = 2 * kp;
    float v0, v1;
    if (k < 100)      { const float* p = we  + word[bt] * 100 + k;         v0 = p[0]; v1 = p[1]; }
    else if (k < 120) { const float* p = te  + tag[bt]  * 20 + (k - 100);  v0 = p[0]; v1 = p[1]; }
    else if (k < 140) { const float* p = p1e + pos1[bt] * 20 + (k - 120);  v0 = p[0]; v1 = p[1]; }
    else              { const float* p = p2e + pos2[bt] * 20 + (k - 140);  v0 = p[0]; v1 = p[1]; }
    emb16[idx] = pack2(v0, v1);
}

// ---------------------------------------------------------------------------
// Phase 0.5: pack input-gate weights to f16 pairs, k-major for coalesced
// staging: wih16[dir][kp(80)][gj(1024)].
// ---------------------------------------------------------------------------
__global__ void wih_pack16(const float* __restrict__ wihf, const float* __restrict__ wihb,
                           unsigned* __restrict__ wp)
{
    int gid = blockIdx.x * 256 + threadIdx.x;   // exactly 2*80*1024 threads
    int dir = gid / 81920;
    int rem = gid - dir * 81920;
    int kp  = rem >> 10;
    int gj  = rem & 1023;
    const float* w = dir ? wihb : wihf;
    const float* row = w + (size_t)gj * IND_ + 2 * kp;
    wp[gid] = pack2(row[0], row[1]);
}

// ---------------------------------------------------------------------------
// Phase 1: input-gate GEMM in f16 dot2 (R8 lever applied here: halves VALU
// and LDS bytes vs fp32 fmaf version).
// xg layout unchanged: [dir][t][bpair(64)][gj(1024)][2]
// ---------------------------------------------------------------------------
__global__ void __launch_bounds__(256) gemm_xg16(
    const unsigned* __restrict__ emb16, const unsigned* __restrict__ wih16,
    const float* __restrict__ bihf, const float* __restrict__ bhhf,
    const float* __restrict__ bihb, const float* __restrict__ bhhb,
    float* __restrict__ xg)
{
    int gt  = blockIdx.x;
    int t   = blockIdx.y;
    int dir = blockIdx.z;
    const unsigned* wbase = wih16 + (size_t)dir * 81920;
    const float* bi = dir ? bihb : bihf;
    const float* bh = dir ? bhhb : bhhf;
    int gj0 = gt * 128;

    __shared__ unsigned wsh[16][132];   // [kp][gj], padded
    __shared__ unsigned esh[16][132];   // [kp][b],  padded

    int tid = threadIdx.x;
    int tx = tid & 15, ty = tid >> 4;

    float acc[8][8];
    #pragma unroll
    for (int i = 0; i < 8; ++i)
        #pragma unroll
        for (int j = 0; j < 8; ++j) acc[i][j] = 0.f;

    for (int kp0 = 0; kp0 < 80; kp0 += 16) {
        __syncthreads();
        #pragma unroll
        for (int m = 0; m < 8; ++m) {
            int e = m * 256 + tid;          // 0..2047
            // wsh: lanes over gj -> coalesced from [kp][gj] packed layout
            int kw = e >> 7, gw = e & 127;
            wsh[kw][gw] = wbase[(kp0 + kw) * 1024 + gj0 + gw];
            // esh: lanes over kp (64B contiguous per b-row)
            int ke = e & 15, ge = e >> 4;
            esh[ke][ge] = emb16[((size_t)ge * L_ + t) * 80 + kp0 + ke];
        }
        __syncthreads();
        #pragma unroll
        for (int kp = 0; kp < 16; ++kp) {
            unsigned wv[8], ev[8];
            #pragma unroll
            for (int q = 0; q < 8; ++q) wv[q] = wsh[kp][ty * 8 + q];
            #pragma unroll
            for (int q = 0; q < 8; ++q) ev[q] = esh[kp][tx * 8 + q];
            #pragma unroll
            for (int i = 0; i < 8; ++i)
                #pragma unroll
                for (int j = 0; j < 8; ++j) acc[i][j] = fdot2_(wv[i], ev[j], acc[i][j]);
        }
    }
    #pragma unroll
    for (int i = 0; i < 8; ++i) {
        int gj = gj0 + ty * 8 + i;
        float bias = bi[gj] + bh[gj];
        #pragma unroll
        for (int j = 0; j < 8; ++j) {
            int b = tx * 8 + j;
            xg[((((size_t)dir * L_ + t) * 64 + (b >> 1)) * 1024 + gj) * 2 + (b & 1)]
                = acc[i][j] + bias;
        }
    }
}

// ---------------------------------------------------------------------------
// Phase 1.5: pack recurrent weights to f16x2 (unchanged).
// ---------------------------------------------------------------------------
__global__ void whh_pack16(const float* __restrict__ whhf, const float* __restrict__ whhb,
                           unsigned* __restrict__ wp)
{
    int gid = blockIdx.x * 256 + threadIdx.x;   // exactly 2*128*256*4 threads
    int g   = gid & 3;
    int h   = (gid >> 2) & 255;
    int p   = (gid >> 10) & 127;
    int dir = gid >> 17;
    const float* whh = dir ? whhb : whhf;
    const float* row = whh + (size_t)(g * 256 + h) * HID_;
    wp[gid] = pack2(row[2 * p], row[2 * p + 1]);
}

// ---------------------------------------------------------------------------
// Phase 2: BiLSTM scan, k-split for wave overlap (R7 verified: ~480us,
// within ~10% of per-CU VMEM floor). Unchanged.
// ---------------------------------------------------------------------------
__global__ void __launch_bounds__(1024, 4) lstm_scan_s(
    const float* __restrict__ xg, const uint4* __restrict__ wp16,
    float* __restrict__ xf2, float* __restrict__ xb2)
{
    int blk = blockIdx.x;
    int dir = blk >> 6;            // 0..1
    int bp  = blk & 63;            // b-pair index
    int tid = threadIdx.x;
    int h   = tid & 255;           // hidden unit
    int q   = tid >> 8;            // k-quarter 0..3 (wave-uniform)

    const uint4* wt = wp16 + (size_t)dir * 128 * 256;   // [p][hid] uint4
    float* xo = dir ? xb2 : xf2;

    __shared__ uint2 hA[128];            // [p] = {bs0 f16x2, bs1 f16x2}
    __shared__ uint2 hB[128];
    __shared__ float pbuf[4][8][256];    // [q][gate*2+bs][h], 32KB
    __shared__ uint4 wlds[SLDS][256];    // q0's p=0..SLDS-1, 96KB

    for (int m = q; m < SLDS; m += 4)
        wlds[m][h] = wt[m * 256 + h];

    if (tid < 256) ((unsigned*)hA)[tid] = 0u;
    float c0 = 0.f, c1 = 0.f;            // live only in q==0 threads
    __syncthreads();

    int pq0  = q * 32;
    int sbeg = (q == 0) ? SLDS : pq0;
    int send = pq0 + 32;

    for (int t = 0; t < L_; ++t) {
        int slot = dir ? (L_ - 1 - t) : t;
        const uint2* hp = (t & 1) ? hB : hA;
        unsigned*    hw = (unsigned*)((t & 1) ? hA : hB);

        float2 gI, gF, gG, gO;
        if (q == 0) {
            const float* xbase = xg + (((size_t)dir * L_ + slot) * 64 + bp) * 2048;
            gI = *(const float2*)(xbase + (0 * 256 + h) * 2);
            gF = *(const float2*)(xbase + (1 * 256 + h) * 2);
            gG = *(const float2*)(xbase + (2 * 256 + h) * 2);
            gO = *(const float2*)(xbase + (3 * 256 + h) * 2);
        }

        float aI0=0.f, aI1=0.f, aF0=0.f, aF1=0.f;
        float aG0=0.f, aG1=0.f, aO0=0.f, aO1=0.f;

        #pragma unroll 8
        for (int p = sbeg; p < send; ++p) {
            uint4 w4 = wt[p * 256 + h];
            uint2 hb = hp[p];
            aI0 = fdot2_(w4.x, hb.x, aI0); aI1 = fdot2_(w4.x, hb.y, aI1);
            aF0 = fdot2_(w4.y, hb.x, aF0); aF1 = fdot2_(w4.y, hb.y, aF1);
            aG0 = fdot2_(w4.z, hb.x, aG0); aG1 = fdot2_(w4.z, hb.y, aG1);
            aO0 = fdot2_(w4.w, hb.x, aO0); aO1 = fdot2_(w4.w, hb.y, aO1);
        }
        if (q == 0) {
            #pragma unroll 8
            for (int p = 0; p < SLDS; ++p) {
                uint4 w4 = wlds[p][h];
                uint2 hb = hp[p];
                aI0 = fdot2_(w4.x, hb.x, aI0); aI1 = fdot2_(w4.x, hb.y, aI1);
                aF0 = fdot2_(w4.y, hb.x, aF0); aF1 = fdot2_(w4.y, hb.y, aF1);
                aG0 = fdot2_(w4.z, hb.x, aG0); aG1 = fdot2_(w4.z, hb.y, aG1);
                aO0 = fdot2_(w4.w, hb.x, aO0); aO1 = fdot2_(w4.w, hb.y, aO1);
            }
        }

        pbuf[q][0][h] = aI0; pbuf[q][1][h] = aI1;
        pbuf[q][2][h] = aF0; pbuf[q][3][h] = aF1;
        pbuf[q][4][h] = aG0; pbuf[q][5][h] = aG1;
        pbuf[q][6][h] = aO0; pbuf[q][7][h] = aO1;
        __syncthreads();

        if (q == 0) {
            float sI0 = pbuf[0][0][h] + pbuf[1][0][h] + pbuf[2][0][h] + pbuf[3][0][h] + gI.x;
            float sI1 = pbuf[0][1][h] + pbuf[1][1][h] + pbuf[2][1][h] + pbuf[3][1][h] + gI.y;
            float sF0 = pbuf[0][2][h] + pbuf[1][2][h] + pbuf[2][2][h] + pbuf[3][2][h] + gF.x;
            float sF1 = pbuf[0][3][h] + pbuf[1][3][h] + pbuf[2][3][h] + pbuf[3][3][h] + gF.y;
            float sG0 = pbuf[0][4][h] + pbuf[1][4][h] + pbuf[2][4][h] + pbuf[3][4][h] + gG.x;
            float sG1 = pbuf[0][5][h] + pbuf[1][5][h] + pbuf[2][5][h] + pbuf[3][5][h] + gG.y;
            float sO0 = pbuf[0][6][h] + pbuf[1][6][h] + pbuf[2][6][h] + pbuf[3][6][h] + gO.x;
            float sO1 = pbuf[0][7][h] + pbuf[1][7][h] + pbuf[2][7][h] + pbuf[3][7][h] + gO.y;

            float i0 = 1.f / (1.f + expf(-sI0));
            float f0 = 1.f / (1.f + expf(-sF0));
            float g0 = tanhf(sG0);
            float o0 = 1.f / (1.f + expf(-sO0));
            c0 = f0 * c0 + i0 * g0;
            float hv0 = o0 * tanhf(c0);

            float i1 = 1.f / (1.f + expf(-sI1));
            float f1 = 1.f / (1.f + expf(-sF1));
            float g1 = tanhf(sG1);
            float o1 = 1.f / (1.f + expf(-sO1));
            c1 = f1 * c1 + i1 * g1;
            float hv1 = o1 * tanhf(c1);

            float n0 = __shfl_xor(hv0, 1);
            float n1 = __shfl_xor(hv1, 1);
            hw[h] = (h & 1) ? pack2(n1, hv1)
                            : pack2(hv0, n0);
            float* xp = xo + ((size_t)slot * 64 + bp) * 512 + h * 2;
            xp[0] = hv0; xp[1] = hv1;
        }
        __syncthreads();
    }
}

// remap [slot][bp][hid*2+bs] -> x[slot][hid][b], summing directions.
__global__ void x_add(const float* __restrict__ xf2, const float* __restrict__ xb2,
                      float* __restrict__ x)
{
    int idx = blockIdx.x * 256 + threadIdx.x;   // exactly L_*HID_*B_ threads
    int b    = idx & 127;
    int j    = (idx >> 7) & 255;
    int slot = idx >> 15;
    int src  = ((slot * 64 + (b >> 1)) * 512) + j * 2 + (b & 1);
    x[idx] = xf2[src] + xb2[src];
}

// ---------------------------------------------------------------------------
// Phase 2.5: pack W_caps to f16 c-pairs (unchanged).
// ---------------------------------------------------------------------------
__global__ void wc_pack16(const float* __restrict__ W, unsigned* __restrict__ wc)
{
    int gid = blockIdx.x * 256 + threadIdx.x;   // exactly 1600*8*304 threads
    int od  = gid % OD;
    int rest = gid / OD;
    int cp  = rest & 7;
    int i   = rest >> 3;
    float a = W[((size_t)i * 16 + 2 * cp) * OD + od];
    float b = W[((size_t)i * 16 + 2 * cp + 1) * OD + od];
    wc[gid] = pack2(a, b);
}

// ---------------------------------------------------------------------------
// Phase 3: attention chain, parallelized & fused.
// compute_he2 folds the entity scan (pos data is L2-resident; redundant
// rescans are cheap) -- removes the single-block find_entity launch.
// ---------------------------------------------------------------------------
__global__ void compute_he2(const int* __restrict__ pos1, const int* __restrict__ pos2,
                            const float* __restrict__ x, float* __restrict__ he)
{
    int j = blockIdx.x, b = threadIdx.x;
    int e1 = 0, e2 = 0;
    for (int l = L_ - 1; l >= 0; --l) if (pos1[b * L_ + l] == ENTITY) e1 = l;
    for (int l = L_ - 1; l >= 0; --l) if (pos2[b * L_ + l] == ENTITY) e2 = l;
    he[j * B_ + b] = x[((size_t)e1 * HID_ + j) * B_ + b] + x[((size_t)e2 * HID_ + j) * B_ + b];
}

// j-chunked logits: 800 blocks (was 100) -> latency hidden by parallelism.
__global__ void att_logits2(const float* __restrict__ x, const float* __restrict__ he,
                            float* __restrict__ lp)
{
    int l = blockIdx.x, jc = blockIdx.y, b = threadIdx.x;
    int j0 = jc * 32;
    float acc = 0.f;
    #pragma unroll
    for (int jj = 0; jj < 32; ++jj) {
        int j = j0 + jj;
        acc = fmaf(x[((size_t)l * HID_ + j) * B_ + b], he[j * B_ + b], acc);
    }
    lp[((size_t)jc * L_ + l) * B_ + b] = acc;
}

// per-b block softmax with LDS tree reduce (was 1 block of 128 threads).
__global__ void att_softmax2(const float* __restrict__ lp, float* __restrict__ att)
{
    int b = blockIdx.x, l = threadIdx.x;    // 128 blocks x 128 threads
    float val = 0.f;
    if (l < L_) {
        #pragma unroll
        for (int jc = 0; jc < 8; ++jc) val += lp[((size_t)jc * L_ + l) * B_ + b];
    }
    __shared__ float red[128];
    red[l] = (l < L_) ? val : -1e30f;
    __syncthreads();
    for (int off = 64; off > 0; off >>= 1) {
        if (l < off) red[l] = fmaxf(red[l], red[l + off]);
        __syncthreads();
    }
    float m = red[0];
    __syncthreads();
    float e = (l < L_) ? expf(val - m) : 0.f;
    red[l] = e;
    __syncthreads();
    for (int off = 64; off > 0; off >>= 1) {
        if (l < off) red[l] += red[l + off];
        __syncthreads();
    }
    float inv = 1.f / red[0];
    if (l < L_) att[l * B_ + b] = e * inv;
}

// primary capsules squashed + packed to f16 c-pairs (unchanged).
__global__ void u_squash16(const float* __restrict__ x, unsigned* __restrict__ u16)
{
    int i = blockIdx.x, b = threadIdx.x;
    int l = i >> 4, cap = i & 15;
    float vals[16]; float n2 = 0.f;
    #pragma unroll
    for (int c2 = 0; c2 < 16; ++c2) {
        float v = x[((size_t)l * HID_ + cap * 16 + c2) * B_ + b];
        vals[c2] = v; n2 = fmaf(v, v, n2);
    }
    float f = (n2 / (1.f + n2)) / sqrtf(n2 + 1e-9f);
    #pragma unroll
    for (int cp = 0; cp < 8; ++cp)
        u16[((size_t)i * B_ + b) * 8 + cp] = pack2(vals[2 * cp] * f, vals[2 * cp + 1] * f);
}

// ---------------------------------------------------------------------------
// Phase 4: routing. First iteration reads br directly (bb_init removed);
// first bb_pass writes br+p instead of +=.
// ---------------------------------------------------------------------------
__global__ void __launch_bounds__(320) s_pass16(
    const unsigned* __restrict__ u16, const unsigned* __restrict__ Wc16,
    const float* __restrict__ bb, const float* __restrict__ br, int first,
    const float* __restrict__ att, float* __restrict__ partial)
{
    int ic = blockIdx.x, bt = blockIdx.y;
    int i0 = ic * 16, b0 = bt * 16;
    __shared__ float C[16][16][20];   // [bl][il][o], padded
    int tid = threadIdx.x;
    if (tid < 256) {
        int bl = tid >> 4, il = tid & 15;
        int b = b0 + bl, i = i0 + il;
        const float* bbp = first ? (br + (size_t)i * NCLASS)
                                 : (bb + ((size_t)b * NI + i) * NCLASS);
        float m = bbp[0];
        #pragma unroll
        for (int o = 1; o < NCLASS; ++o) m = fmaxf(m, bbp[o]);
        float s = 0.f; float e[NCLASS];
        #pragma unroll
        for (int o = 0; o < NCLASS; ++o) { e[o] = expf(bbp[o] - m); s += e[o]; }
        float al = att[(i >> 4) * B_ + b] / s;
        #pragma unroll
        for (int o = 0; o < NCLASS; ++o) C[bl][il][o] = e[o] * al;
    }
    __syncthreads();
    if (tid >= OD) return;
    int od = tid, o = od >> 4;
    float acc[16];
    #pragma unroll
    for (int bl = 0; bl < 16; ++bl) acc[bl] = 0.f;
    for (int il = 0; il < 16; ++il) {
        int i = i0 + il;
        const unsigned* wp = Wc16 + (size_t)i * 8 * OD + od;
        unsigned w2[8];
        #pragma unroll
        for (int cp = 0; cp < 8; ++cp) w2[cp] = wp[cp * OD];
        const unsigned* up = u16 + ((size_t)i * B_ + b0) * 8;
        #pragma unroll
        for (int bl = 0; bl < 16; ++bl) {
            float uh = 0.f;
            #pragma unroll
            for (int cp = 0; cp < 8; ++cp) uh = fdot2_(up[bl * 8 + cp], w2[cp], uh);
            acc[bl] = fmaf(C[bl][il][o], uh, acc[bl]);
        }
    }
    #pragma unroll
    for (int bl = 0; bl < 16; ++bl)
        partial[((size_t)ic * B_ + b0 + bl) * OD + od] = acc[bl];
}

__global__ void s_reduce(const float* __restrict__ partial, float* __restrict__ s)
{
    int idx = blockIdx.x * 256 + threadIdx.x;   // exactly B_*OD threads
    int b = idx / OD, od = idx - b * OD;
    float acc = 0.f;
    for (int ic = 0; ic < 100; ++ic) acc += partial[((size_t)ic * B_ + b) * OD + od];
    s[idx] = acc;
}

__global__ void squash_v(const float* __restrict__ s, float* __restrict__ v,
                         float* __restrict__ out, int write_out)
{
    int idx = blockIdx.x * 256 + threadIdx.x;
    if (idx >= B_ * NCLASS) return;
    const float* sp = s + (size_t)idx * 16;
    float vals[16]; float n2 = 0.f;
    #pragma unroll
    for (int d = 0; d < 16; ++d) { vals[d] = sp[d]; n2 = fmaf(vals[d], vals[d], n2); }
    float f = (n2 / (1.f + n2)) / sqrtf(n2 + 1e-9f);
    float n2v = 0.f;
    #pragma unroll
    for (int d = 0; d < 16; ++d) {
        float vv = vals[d] * f;
        v[(size_t)idx * 16 + d] = vv;
        n2v = fmaf(vv, vv, n2v);
    }
    if (write_out) out[idx] = sqrtf(n2v + 1e-9f);
}

__global__ void __launch_bounds__(320) bb_pass16(
    const unsigned* __restrict__ u16, const unsigned* __restrict__ Wc16,
    const float* __restrict__ v, float* __restrict__ bb,
    const float* __restrict__ br, int first)
{
    int ic = blockIdx.x, bt = blockIdx.y;
    int i0 = ic * 16, b0 = bt * 16;
    int tid = threadIdx.x;
    if (tid >= OD) return;
    int od = tid, o = od >> 4, d = od & 15;
    float vv[16];
    #pragma unroll
    for (int bl = 0; bl < 16; ++bl) vv[bl] = v[(size_t)(b0 + bl) * OD + od];
    for (int il = 0; il < 16; ++il) {
        int i = i0 + il;
        const unsigned* wp = Wc16 + (size_t)i * 8 * OD + od;
        unsigned w2[8];
        #pragma unroll
        for (int cp = 0; cp < 8; ++cp) w2[cp] = wp[cp * OD];
        const unsigned* up = u16 + ((size_t)i * B_ + b0) * 8;
        #pragma unroll
        for (int bl = 0; bl < 16; ++bl) {
            float uh = 0.f;
            #pragma unroll
            for (int cp = 0; cp < 8; ++cp) uh = fdot2_(up[bl * 8 + cp], w2[cp], uh);
            float p = uh * vv[bl];
            p += __shfl_xor(p, 1);
            p += __shfl_xor(p, 2);
            p += __shfl_xor(p, 4);
            p += __shfl_xor(p, 8);
            if (d == 0) {
                size_t off = ((size_t)(b0 + bl) * NI + i) * NCLASS + o;
                bb[off] = (first ? br[(size_t)i * NCLASS + o] : bb[off]) + p;
            }
        }
    }
}

// ---------------------------------------------------------------------------
extern "C" void kernel_launch(void* const* d_in, const int* in_sizes, int n_in,
                              void* d_out, int out_size, void* d_ws, size_t ws_size,
                              hipStream_t stream)
{
    (void)in_sizes; (void)n_in; (void)out_size; (void)ws_size;
    const int*   word = (const int*)d_in[0];
    const int*   tag  = (const int*)d_in[1];
    const int*   pos1 = (const int*)d_in[2];
    const int*   pos2 = (const int*)d_in[3];
    const float* we   = (const float*)d_in[4];
    const float* te   = (const float*)d_in[5];
    const float* p1e  = (const float*)d_in[6];
    const float* p2e  = (const float*)d_in[7];
    const float* wihf = (const float*)d_in[8];
    const float* whhf = (const float*)d_in[9];
    const float* bihf = (const float*)d_in[10];
    const float* bhhf = (const float*)d_in[11];
    const float* wihb = (const float*)d_in[12];
    const float* whhb = (const float*)d_in[13];
    const float* bihb = (const float*)d_in[14];
    const float* bhhb = (const float*)d_in[15];
    const float* Wc   = (const float*)d_in[16];
    const float* br   = (const float*)d_in[17];

    float* wsp = (float*)d_ws;
    // packed-input region (old emb area, 2,048,000 floats):
    unsigned* emb16 = (unsigned*)wsp;                    // 1,024,000 uints
    unsigned* wih16 = (unsigned*)(wsp + 1024000);        //   163,840 uints
    unsigned* wp16  = (unsigned*)(wsp + 1024000 + 163840); // 262,144 uints
    float* xg  = wsp + 2048000;                // 26,214,400
    float* xf  = xg + 26214400;                //  3,276,800
    float* xb  = xf + 3276800;                 //  3,276,800
    float* he  = xb + 3276800;                 //     32,768
    float* att = he + 32768;                   //     12,800
    // packed f16 W_caps spans xf and part of xb (both dead after x_add)
    unsigned* Wc16 = (unsigned*)xf;            //  3,891,200 uints
    float*    lp   = xf + 3891200;             //    102,400 (xb tail, free)
    // post-scan buffers alias the (dead-after-scan) xg region
    float*    x    = xg;                       //  3,276,800
    unsigned* u16  = (unsigned*)(xg + 3276800);//  1,638,400 uints
    float*    bb   = xg + 6553600;             //  3,891,200
    float*    part = xg + 10444800;            //  3,891,200
    float*    s    = xg + 14336000;            //     38,912
    float*    v    = s + 38912;                //     38,912
    float*    out  = (float*)d_out;

    emb_gather16<<<4000, 256, 0, stream>>>(word, tag, pos1, pos2, we, te, p1e, p2e, emb16);
    wih_pack16<<<640, 256, 0, stream>>>(wihf, wihb, wih16);
    whh_pack16<<<1024, 256, 0, stream>>>(whhf, whhb, wp16);
    gemm_xg16<<<dim3(8, 100, 2), 256, 0, stream>>>(emb16, wih16, bihf, bhhf, bihb, bhhb, xg);
    lstm_scan_s<<<128, 1024, 0, stream>>>(xg, (const uint4*)wp16, xf, xb);
    x_add<<<12800, 256, 0, stream>>>(xf, xb, x);
    wc_pack16<<<15200, 256, 0, stream>>>(Wc, Wc16);   // after x_add: xf/xb dead
    compute_he2<<<256, 128, 0, stream>>>(pos1, pos2, x, he);
    att_logits2<<<dim3(100, 8), 128, 0, stream>>>(x, he, lp);
    att_softmax2<<<128, 128, 0, stream>>>(lp, att);
    u_squash16<<<1600, 128, 0, stream>>>(x, u16);
    for (int it = 0; it < 3; ++it) {
        s_pass16<<<dim3(100, 8), 320, 0, stream>>>(u16, Wc16, bb, br, it == 0, att, part);
        s_reduce<<<152, 256, 0, stream>>>(part, s);
        squash_v<<<10, 256, 0, stream>>>(s, v, out, (it == 2) ? 1 : 0);
        if (it < 2) bb_pass16<<<dim3(100, 8), 320, 0, stream>>>(u16, Wc16, v, bb, br, it == 0);
    }
}